// Round 1
// baseline (5826.554 us; speedup 1.0000x reference)
//
#include <hip/hip_runtime.h>
#include <hip/hip_bf16.h>
#include <math.h>

// Model dims (compile-time constants)
#define NL 4
#define DM 768
#define DI 1536
#define DS 16
#define DTR 48
#define DCONV 4
#define VOCAB_ 32000
#define BB 2
#define LL 512
#define ROWS (BB*LL)   // 1024

// ---------------------------------------------------------------------------
// Embedding gather: h[b,l,:] = embed[ids[b,l],:]
// ---------------------------------------------------------------------------
__global__ __launch_bounds__(256) void gather_kernel(
    const int* __restrict__ ids, const float* __restrict__ embed,
    float* __restrict__ h, int n)
{
    int idx = blockIdx.x * 256 + threadIdx.x;
    if (idx >= n) return;
    int d = idx % DM;
    int tok = idx / DM;
    h[idx] = embed[(size_t)ids[tok] * DM + d];
}

// ---------------------------------------------------------------------------
// RMSNorm: one block per row, D elements
// ---------------------------------------------------------------------------
__global__ __launch_bounds__(256) void rmsnorm_kernel(
    const float* __restrict__ x, const float* __restrict__ w,
    float* __restrict__ out, int D)
{
    int row = blockIdx.x;
    const float* xr = x + (size_t)row * D;
    float ss = 0.f;
    for (int i = threadIdx.x; i < D; i += 256) { float v = xr[i]; ss += v * v; }
    // wave64 butterfly
    for (int o = 32; o >= 1; o >>= 1) ss += __shfl_xor(ss, o, 64);
    __shared__ float sbuf[4];
    int wid = threadIdx.x >> 6;
    if ((threadIdx.x & 63) == 0) sbuf[wid] = ss;
    __syncthreads();
    if (threadIdx.x == 0) {
        float t = sbuf[0] + sbuf[1] + sbuf[2] + sbuf[3];
        sbuf[0] = 1.0f / sqrtf(t / (float)D + 1e-5f);
    }
    __syncthreads();
    float scale = sbuf[0];
    for (int i = threadIdx.x; i < D; i += 256)
        out[(size_t)row * D + i] = xr[i] * scale * w[i];
}

// ---------------------------------------------------------------------------
// Generic fp32 GEMM: C[M,N] = A[M,K] @ W[N,K]^T  (+ epilogue)
// EPI: 0 = none, 1 = +bias then softplus, 2 = +resid (residual add)
// 64x64 block tile, BK=16, 256 threads, 4x4 microtile per thread
// ---------------------------------------------------------------------------
template<int EPI>
__global__ __launch_bounds__(256) void gemm_tn(
    const float* __restrict__ A, int lda,
    const float* __restrict__ W, int ldw,
    float* __restrict__ C, int ldc,
    int M, int N, int K,
    const float* __restrict__ bias,
    const float* __restrict__ resid)
{
    const int tid = threadIdx.x;
    const int tx = tid & 15;        // 0..15 -> N micro
    const int ty = tid >> 4;        // 0..15 -> M micro
    const int m0 = blockIdx.x * 64;
    const int n0 = blockIdx.y * 64;

    __shared__ float As[16][65];    // [k][m], padded
    __shared__ float Ws[16][65];    // [k][n], padded

    float acc[4][4];
    #pragma unroll
    for (int i = 0; i < 4; i++)
        #pragma unroll
        for (int j = 0; j < 4; j++) acc[i][j] = 0.f;

    const int lrow = tid >> 2;          // 0..63
    const int lk   = (tid & 3) * 4;     // 0,4,8,12

    for (int k0 = 0; k0 < K; k0 += 16) {
        {
            int m = m0 + lrow;
            int n = n0 + lrow;
            #pragma unroll
            for (int j = 0; j < 4; j++) {
                int k = k0 + lk + j;
                As[lk + j][lrow] = (m < M && k < K) ? A[(size_t)m * lda + k] : 0.f;
                Ws[lk + j][lrow] = (n < N && k < K) ? W[(size_t)n * ldw + k] : 0.f;
            }
        }
        __syncthreads();
        #pragma unroll
        for (int k = 0; k < 16; k++) {
            float a[4], w[4];
            #pragma unroll
            for (int i = 0; i < 4; i++) a[i] = As[k][ty * 4 + i];
            #pragma unroll
            for (int j = 0; j < 4; j++) w[j] = Ws[k][tx * 4 + j];
            #pragma unroll
            for (int i = 0; i < 4; i++)
                #pragma unroll
                for (int j = 0; j < 4; j++)
                    acc[i][j] += a[i] * w[j];
        }
        __syncthreads();
    }

    #pragma unroll
    for (int i = 0; i < 4; i++) {
        int m = m0 + ty * 4 + i;
        if (m >= M) continue;
        #pragma unroll
        for (int j = 0; j < 4; j++) {
            int n = n0 + tx * 4 + j;
            if (n >= N) continue;
            float v = acc[i][j];
            if (EPI == 1) {
                v += bias[n];
                // stable softplus = max(v,0) + log1p(exp(-|v|))  (== jax.nn.softplus)
                v = fmaxf(v, 0.f) + log1pf(expf(-fabsf(v)));
            }
            if (EPI == 2) v += resid[(size_t)m * ldc + n];
            C[(size_t)m * ldc + n] = v;
        }
    }
}

// ---------------------------------------------------------------------------
// Causal depthwise conv (k=4) + SiLU.
// Input: proj [ROWS, 2*DI], h part = cols 0..DI-1. Output hconv [ROWS, DI].
// ---------------------------------------------------------------------------
__global__ __launch_bounds__(256) void conv_silu_kernel(
    const float* __restrict__ proj,
    const float* __restrict__ cw,   // [DI, 4]
    const float* __restrict__ cb,   // [DI]
    float* __restrict__ hconv)
{
    int idx = blockIdx.x * 256 + threadIdx.x;   // over ROWS*DI
    if (idx >= ROWS * DI) return;
    int d = idx % DI;
    int bt = idx / DI;
    int t = bt % LL;
    float sum = cb[d];
    #pragma unroll
    for (int j = 0; j < DCONV; j++) {
        int tt = t - (DCONV - 1) + j;
        if (tt >= 0)
            sum += cw[d * DCONV + j] * proj[(size_t)(bt - (DCONV - 1) + j) * (2 * DI) + d];
    }
    float sig = 1.f / (1.f + expf(-sum));
    hconv[idx] = sum * sig;
}

// ---------------------------------------------------------------------------
// Fused selective scan. One thread per (b, d, s); state lives in a register.
// Block = 256 threads = 16 d-groups x 16 s-lanes. Grid = B * (DI/16) = 192.
// y[b,t,d] = (sum_s state*C + D_skip[d]*h) * silu(gate)
// ---------------------------------------------------------------------------
__global__ __launch_bounds__(256) void scan_kernel(
    const float* __restrict__ dt,     // [ROWS, DI] (post-softplus)
    const float* __restrict__ hconv,  // [ROWS, DI]
    const float* __restrict__ ssm,    // [ROWS, DTR+2*DS]; B at +DTR, C at +DTR+DS
    const float* __restrict__ proj,   // [ROWS, 2*DI]; gate at +DI
    const float* __restrict__ A_log,  // [DI, DS]
    const float* __restrict__ D_skip, // [DI]
    float* __restrict__ y)            // [ROWS, DI]
{
    const int tid = threadIdx.x;
    const int s  = tid & 15;
    const int dg = tid >> 4;                 // 0..15
    const int b    = blockIdx.x / (DI / 16);
    const int dblk = blockIdx.x % (DI / 16);
    const int d = dblk * 16 + dg;

    const float Ads = -expf(A_log[(size_t)d * DS + s]);
    const float Dd  = D_skip[d];
    float state = 0.f;

    const float* dtp = dt    + (size_t)b * LL * DI + d;
    const float* hp  = hconv + (size_t)b * LL * DI + d;
    const float* gp  = proj  + (size_t)b * LL * (2 * DI) + DI + d;
    const float* sp  = ssm   + (size_t)b * LL * (DTR + 2 * DS);
    float*       yp  = y     + (size_t)b * LL * DI + d;

    for (int t = 0; t < LL; ++t) {
        float dtv = dtp[(size_t)t * DI];
        float hv  = hp[(size_t)t * DI];
        float Bv  = sp[(size_t)t * (DTR + 2 * DS) + DTR + s];
        float Cv  = sp[(size_t)t * (DTR + 2 * DS) + DTR + DS + s];
        float dA  = expf(dtv * Ads);
        state = dA * state + dtv * hv * Bv;
        float contrib = state * Cv;
        contrib += __shfl_xor(contrib, 1, 16);
        contrib += __shfl_xor(contrib, 2, 16);
        contrib += __shfl_xor(contrib, 4, 16);
        contrib += __shfl_xor(contrib, 8, 16);
        if (s == 0) {
            float gv = gp[(size_t)t * (2 * DI)];
            float sig = 1.f / (1.f + expf(-gv));
            yp[(size_t)t * DI] = (contrib + Dd * hv) * (gv * sig);
        }
    }
}

// ---------------------------------------------------------------------------
// Launch
// ---------------------------------------------------------------------------
extern "C" void kernel_launch(void* const* d_in, const int* in_sizes, int n_in,
                              void* d_out, int out_size, void* d_ws, size_t ws_size,
                              hipStream_t stream)
{
    const int*   ids        = (const int*)  d_in[0];
    const float* embed      = (const float*)d_in[1];
    const float* norm_f_w   = (const float*)d_in[2];
    const float* in_proj_w  = (const float*)d_in[3];
    const float* conv_w     = (const float*)d_in[4];
    const float* conv_b     = (const float*)d_in[5];
    const float* x_proj_w   = (const float*)d_in[6];
    const float* dt_proj_w  = (const float*)d_in[7];
    const float* dt_proj_b  = (const float*)d_in[8];
    const float* A_log      = (const float*)d_in[9];
    const float* D_skip     = (const float*)d_in[10];
    const float* out_proj_w = (const float*)d_in[11];
    const float* norm_w     = (const float*)d_in[12];
    float* out = (float*)d_out;

    // workspace layout (floats)
    float* ws    = (float*)d_ws;
    float* h     = ws;                       // ROWS*DM      = 786432
    float* xn    = h     + ROWS * DM;        // ROWS*DM      = 786432
    float* proj  = xn    + ROWS * DM;        // ROWS*2*DI    = 3145728
    float* hconv = proj  + ROWS * 2 * DI;    // ROWS*DI      = 1572864
    float* ssm   = hconv + ROWS * DI;        // ROWS*80      = 81920
    float* dtb   = ssm   + ROWS * (DTR + 2 * DS); // ROWS*DI = 1572864
    float* yb    = dtb   + ROWS * DI;        // ROWS*DI      = 1572864

    const int SSMW = DTR + 2 * DS;           // 80

    // embed gather
    gather_kernel<<<(ROWS * DM + 255) / 256, 256, 0, stream>>>(ids, embed, h, ROWS * DM);

    for (int i = 0; i < NL; ++i) {
        const float* ipw = in_proj_w  + (size_t)i * 2 * DI * DM;
        const float* cw  = conv_w     + (size_t)i * DI * DCONV;
        const float* cb  = conv_b     + (size_t)i * DI;
        const float* xpw = x_proj_w   + (size_t)i * SSMW * DI;
        const float* dpw = dt_proj_w  + (size_t)i * DI * DTR;
        const float* dpb = dt_proj_b  + (size_t)i * DI;
        const float* al  = A_log      + (size_t)i * DI * DS;
        const float* dsk = D_skip     + (size_t)i * DI;
        const float* opw = out_proj_w + (size_t)i * DM * DI;
        const float* nw  = norm_w     + (size_t)i * DM;

        // xn = rmsnorm(h)
        rmsnorm_kernel<<<ROWS, 256, 0, stream>>>(h, nw, xn, DM);
        // proj = xn @ in_proj_w^T   [1024, 3072]
        gemm_tn<0><<<dim3(ROWS / 64, (2 * DI) / 64), 256, 0, stream>>>(
            xn, DM, ipw, DM, proj, 2 * DI, ROWS, 2 * DI, DM, nullptr, nullptr);
        // hconv = silu(causal depthwise conv(proj[:, :DI]))
        conv_silu_kernel<<<(ROWS * DI + 255) / 256, 256, 0, stream>>>(proj, cw, cb, hconv);
        // ssm = hconv @ x_proj_w^T  [1024, 80]
        gemm_tn<0><<<dim3(ROWS / 64, (SSMW + 63) / 64), 256, 0, stream>>>(
            hconv, DI, xpw, DI, ssm, SSMW, ROWS, SSMW, DI, nullptr, nullptr);
        // dt = softplus(ssm[:, :48] @ dt_proj_w^T + b)  [1024, 1536]
        gemm_tn<1><<<dim3(ROWS / 64, DI / 64), 256, 0, stream>>>(
            ssm, SSMW, dpw, DTR, dtb, DI, ROWS, DI, DTR, dpb, nullptr);
        // fused selective scan -> yb  [1024, 1536]
        scan_kernel<<<BB * (DI / 16), 256, 0, stream>>>(dtb, hconv, ssm, proj, al, dsk, yb);
        // h = h + yb @ out_proj_w^T  [1024, 768]
        gemm_tn<2><<<dim3(ROWS / 64, DM / 64), 256, 0, stream>>>(
            yb, DI, opw, DI, h, DM, ROWS, DM, DI, nullptr, h);
    }

    // final norm + tied lm head
    rmsnorm_kernel<<<ROWS, 256, 0, stream>>>(h, norm_f_w, xn, DM);
    gemm_tn<0><<<dim3(ROWS / 64, VOCAB_ / 64), 256, 0, stream>>>(
        xn, DM, embed, DM, out, VOCAB_, ROWS, VOCAB_, DM, nullptr, nullptr);
}

// Round 3
// 3447.659 us; speedup vs baseline: 1.6900x; 1.6900x over previous
//
#include <hip/hip_runtime.h>
#include <hip/hip_bf16.h>
#include <math.h>

// Model dims (compile-time constants)
#define NL 4
#define DM 768
#define DI 1536
#define DS 16
#define DTR 48
#define DCONV 4
#define VOCAB_ 32000
#define BB 2
#define LL 512
#define ROWS (BB*LL)   // 1024
#define SSMW (DTR + 2*DS)  // 80

typedef __bf16 bf16x8 __attribute__((ext_vector_type(8)));
typedef float f32x4 __attribute__((ext_vector_type(4)));

// ---------------------------------------------------------------------------
// fp32 -> bf16 split helpers (RNE)
// ---------------------------------------------------------------------------
__device__ __forceinline__ unsigned short f2bf(float f) {
    unsigned u = __float_as_uint(f);
    u = u + 0x7fffu + ((u >> 16) & 1u);
    return (unsigned short)(u >> 16);
}
__device__ __forceinline__ float bf2f(unsigned short b) {
    return __uint_as_float((unsigned)b << 16);
}

// Split fp32 tensor into hi/lo bf16 planes. n4 = n/4 (n always multiple of 4).
__global__ __launch_bounds__(256) void split_kernel(
    const float* __restrict__ x,
    unsigned short* __restrict__ hi, unsigned short* __restrict__ lo, int n4)
{
    int i = blockIdx.x * 256 + threadIdx.x;
    if (i >= n4) return;
    const float4 v = ((const float4*)x)[i];
    float vv[4] = {v.x, v.y, v.z, v.w};
    unsigned short hh[4], ll[4];
    #pragma unroll
    for (int j = 0; j < 4; j++) {
        hh[j] = f2bf(vv[j]);
        ll[j] = f2bf(vv[j] - bf2f(hh[j]));   // exact residual
    }
    ((ushort4*)hi)[i] = make_ushort4(hh[0], hh[1], hh[2], hh[3]);
    ((ushort4*)lo)[i] = make_ushort4(ll[0], ll[1], ll[2], ll[3]);
}

// ---------------------------------------------------------------------------
// global -> LDS 16B async copy
// ---------------------------------------------------------------------------
__device__ __forceinline__ void gld16(void* l, const void* g) {
    __builtin_amdgcn_global_load_lds(
        (const __attribute__((address_space(1))) void*)g,
        (__attribute__((address_space(3))) void*)l, 16, 0, 0);
}

// ---------------------------------------------------------------------------
// bf16x3 MFMA GEMM: C[M,N] = A[M,K] @ W[N,K]^T with split-precision operands.
// A = Ahi+Alo, W = Bhi+Blo (bf16 planes). Computes hi*hi + hi*lo + lo*hi.
// 128x128 tile, BK=32, 256 threads = 4 waves (2x2), 64x64 per wave.
// M, N multiples of 128; K multiple of 32.
// EPI: 0 = none, 2 = +resid
// LDS layout per plane: [128 rows][4 slots of 16B], physical slot = slot ^ ((row>>1)&3)
// (inverse swizzle applied on the global source; reads are conflict-free b128)
// ---------------------------------------------------------------------------
template<int EPI>
__global__ __launch_bounds__(256) void gemm_mfma(
    const unsigned short* __restrict__ Ahi, const unsigned short* __restrict__ Alo, int lda,
    const unsigned short* __restrict__ Bhi, const unsigned short* __restrict__ Blo, int ldb,
    float* __restrict__ C, int ldc, int K,
    const float* __restrict__ resid)
{
    __shared__ __align__(16) unsigned short sAh[128*32];
    __shared__ __align__(16) unsigned short sAl[128*32];
    __shared__ __align__(16) unsigned short sBh[128*32];
    __shared__ __align__(16) unsigned short sBl[128*32];

    const int tid  = threadIdx.x;
    const int lane = tid & 63;
    const int m0 = blockIdx.x * 128;
    const int n0 = blockIdx.y * 128;
    const int w  = tid >> 6;
    const int wr = (w >> 1) * 64;   // wave row offset
    const int wc = (w & 1) * 64;    // wave col offset

    f32x4 acc[4][4];
    #pragma unroll
    for (int i = 0; i < 4; i++)
        #pragma unroll
        for (int j = 0; j < 4; j++)
            acc[i][j] = (f32x4){0.f, 0.f, 0.f, 0.f};

    // staging coords: thread covers physical slot (srow, ps) and (srow+64, ps)
    const int srow = tid >> 2;
    const int ps   = tid & 3;
    const int lsl  = ps ^ ((srow >> 1) & 3);   // logical k-slot (same for srow+64)

    // fragment read offsets (in ushorts), fixed per thread
    int offA[4], offB[4];
    #pragma unroll
    for (int i = 0; i < 4; i++) {
        int ra = wr + i*16 + (lane & 15);
        int pa = (lane >> 4) ^ ((ra >> 1) & 3);
        offA[i] = ra*32 + pa*8;
        int rb = wc + i*16 + (lane & 15);
        int pb = (lane >> 4) ^ ((rb >> 1) & 3);
        offB[i] = rb*32 + pb*8;
    }

    for (int k0 = 0; k0 < K; k0 += 32) {
        const size_t a1 = (size_t)(m0 + srow)      * lda + k0 + lsl*8;
        const size_t a2 = (size_t)(m0 + 64 + srow) * lda + k0 + lsl*8;
        const size_t b1 = (size_t)(n0 + srow)      * ldb + k0 + lsl*8;
        const size_t b2 = (size_t)(n0 + 64 + srow) * ldb + k0 + lsl*8;
        gld16(&sAh[(size_t)tid*8],       Ahi + a1);
        gld16(&sAh[(size_t)(256+tid)*8], Ahi + a2);
        gld16(&sAl[(size_t)tid*8],       Alo + a1);
        gld16(&sAl[(size_t)(256+tid)*8], Alo + a2);
        gld16(&sBh[(size_t)tid*8],       Bhi + b1);
        gld16(&sBh[(size_t)(256+tid)*8], Bhi + b2);
        gld16(&sBl[(size_t)tid*8],       Blo + b1);
        gld16(&sBl[(size_t)(256+tid)*8], Blo + b2);
        __syncthreads();   // compiler drains vmcnt before s_barrier

        bf16x8 ah[4], al[4], bh[4], bl[4];
        #pragma unroll
        for (int i = 0; i < 4; i++) {
            ah[i] = *(const bf16x8*)&sAh[offA[i]];
            al[i] = *(const bf16x8*)&sAl[offA[i]];
            bh[i] = *(const bf16x8*)&sBh[offB[i]];
            bl[i] = *(const bf16x8*)&sBl[offB[i]];
        }
        #pragma unroll
        for (int i = 0; i < 4; i++)
            #pragma unroll
            for (int j = 0; j < 4; j++) {
                acc[i][j] = __builtin_amdgcn_mfma_f32_16x16x32_bf16(ah[i], bh[j], acc[i][j], 0, 0, 0);
                acc[i][j] = __builtin_amdgcn_mfma_f32_16x16x32_bf16(ah[i], bl[j], acc[i][j], 0, 0, 0);
                acc[i][j] = __builtin_amdgcn_mfma_f32_16x16x32_bf16(al[i], bh[j], acc[i][j], 0, 0, 0);
            }
        __syncthreads();
    }

    // epilogue: D[row=(lane>>4)*4+r][col=lane&15] per 16x16 frag (HW-verified layout)
    #pragma unroll
    for (int i = 0; i < 4; i++) {
        int rbase = m0 + wr + i*16 + (lane >> 4)*4;
        #pragma unroll
        for (int j = 0; j < 4; j++) {
            int col = n0 + wc + j*16 + (lane & 15);
            #pragma unroll
            for (int r = 0; r < 4; r++) {
                float v = acc[i][j][r];
                if (EPI == 2) v += resid[(size_t)(rbase + r)*ldc + col];
                C[(size_t)(rbase + r)*ldc + col] = v;
            }
        }
    }
}

// ---------------------------------------------------------------------------
// Embedding gather
// ---------------------------------------------------------------------------
__global__ __launch_bounds__(256) void gather_kernel(
    const int* __restrict__ ids, const float* __restrict__ embed,
    float* __restrict__ h, int n)
{
    int idx = blockIdx.x * 256 + threadIdx.x;
    if (idx >= n) return;
    int d = idx % DM;
    int tok = idx / DM;
    h[idx] = embed[(size_t)ids[tok] * DM + d];
}

// ---------------------------------------------------------------------------
// RMSNorm
// ---------------------------------------------------------------------------
__global__ __launch_bounds__(256) void rmsnorm_kernel(
    const float* __restrict__ x, const float* __restrict__ w,
    float* __restrict__ out, int D)
{
    int row = blockIdx.x;
    const float* xr = x + (size_t)row * D;
    float ss = 0.f;
    for (int i = threadIdx.x; i < D; i += 256) { float v = xr[i]; ss += v * v; }
    for (int o = 32; o >= 1; o >>= 1) ss += __shfl_xor(ss, o, 64);
    __shared__ float sbuf[4];
    int wid = threadIdx.x >> 6;
    if ((threadIdx.x & 63) == 0) sbuf[wid] = ss;
    __syncthreads();
    if (threadIdx.x == 0) {
        float t = sbuf[0] + sbuf[1] + sbuf[2] + sbuf[3];
        sbuf[0] = 1.0f / sqrtf(t / (float)D + 1e-5f);
    }
    __syncthreads();
    float scale = sbuf[0];
    for (int i = threadIdx.x; i < D; i += 256)
        out[(size_t)row * D + i] = xr[i] * scale * w[i];
}

// ---------------------------------------------------------------------------
// fp32 fallback GEMM (x_proj / dt_proj and small-ws fallback)
// EPI: 0 = none, 1 = +bias softplus, 2 = +resid
// ---------------------------------------------------------------------------
template<int EPI>
__global__ __launch_bounds__(256) void gemm_tn(
    const float* __restrict__ A, int lda,
    const float* __restrict__ W, int ldw,
    float* __restrict__ C, int ldc,
    int M, int N, int K,
    const float* __restrict__ bias,
    const float* __restrict__ resid)
{
    const int tid = threadIdx.x;
    const int tx = tid & 15;
    const int ty = tid >> 4;
    const int m0 = blockIdx.x * 64;
    const int n0 = blockIdx.y * 64;

    __shared__ float As[16][65];
    __shared__ float Ws[16][65];

    float acc[4][4];
    #pragma unroll
    for (int i = 0; i < 4; i++)
        #pragma unroll
        for (int j = 0; j < 4; j++) acc[i][j] = 0.f;

    const int lrow = tid >> 2;
    const int lk   = (tid & 3) * 4;

    for (int k0 = 0; k0 < K; k0 += 16) {
        {
            int m = m0 + lrow;
            int n = n0 + lrow;
            #pragma unroll
            for (int j = 0; j < 4; j++) {
                int k = k0 + lk + j;
                As[lk + j][lrow] = (m < M && k < K) ? A[(size_t)m * lda + k] : 0.f;
                Ws[lk + j][lrow] = (n < N && k < K) ? W[(size_t)n * ldw + k] : 0.f;
            }
        }
        __syncthreads();
        #pragma unroll
        for (int k = 0; k < 16; k++) {
            float a[4], wv[4];
            #pragma unroll
            for (int i = 0; i < 4; i++) a[i] = As[k][ty * 4 + i];
            #pragma unroll
            for (int j = 0; j < 4; j++) wv[j] = Ws[k][tx * 4 + j];
            #pragma unroll
            for (int i = 0; i < 4; i++)
                #pragma unroll
                for (int j = 0; j < 4; j++)
                    acc[i][j] += a[i] * wv[j];
        }
        __syncthreads();
    }

    #pragma unroll
    for (int i = 0; i < 4; i++) {
        int m = m0 + ty * 4 + i;
        if (m >= M) continue;
        #pragma unroll
        for (int j = 0; j < 4; j++) {
            int n = n0 + tx * 4 + j;
            if (n >= N) continue;
            float v = acc[i][j];
            if (EPI == 1) {
                v += bias[n];
                v = fmaxf(v, 0.f) + log1pf(expf(-fabsf(v)));
            }
            if (EPI == 2) v += resid[(size_t)m * ldc + n];
            C[(size_t)m * ldc + n] = v;
        }
    }
}

// ---------------------------------------------------------------------------
// Causal depthwise conv (k=4) + SiLU
// ---------------------------------------------------------------------------
__global__ __launch_bounds__(256) void conv_silu_kernel(
    const float* __restrict__ proj,
    const float* __restrict__ cw, const float* __restrict__ cb,
    float* __restrict__ hconv)
{
    int idx = blockIdx.x * 256 + threadIdx.x;
    if (idx >= ROWS * DI) return;
    int d = idx % DI;
    int bt = idx / DI;
    int t = bt % LL;
    float sum = cb[d];
    #pragma unroll
    for (int j = 0; j < DCONV; j++) {
        int tt = t - (DCONV - 1) + j;
        if (tt >= 0)
            sum += cw[d * DCONV + j] * proj[(size_t)(bt - (DCONV - 1) + j) * (2 * DI) + d];
    }
    float sig = 1.f / (1.f + expf(-sum));
    hconv[idx] = sum * sig;
}

// ---------------------------------------------------------------------------
// Fused selective scan (state in register; 16 s-lanes reduce via shfl)
// ---------------------------------------------------------------------------
__global__ __launch_bounds__(256) void scan_kernel(
    const float* __restrict__ dt, const float* __restrict__ hconv,
    const float* __restrict__ ssm, const float* __restrict__ proj,
    const float* __restrict__ A_log, const float* __restrict__ D_skip,
    float* __restrict__ y)
{
    const int tid = threadIdx.x;
    const int s  = tid & 15;
    const int dg = tid >> 4;
    const int b    = blockIdx.x / (DI / 16);
    const int dblk = blockIdx.x % (DI / 16);
    const int d = dblk * 16 + dg;

    const float Ads = -expf(A_log[(size_t)d * DS + s]);
    const float Dd  = D_skip[d];
    float state = 0.f;

    const float* dtp = dt    + (size_t)b * LL * DI + d;
    const float* hp  = hconv + (size_t)b * LL * DI + d;
    const float* gp  = proj  + (size_t)b * LL * (2 * DI) + DI + d;
    const float* sp  = ssm   + (size_t)b * LL * SSMW;
    float*       yp  = y     + (size_t)b * LL * DI + d;

    for (int t = 0; t < LL; ++t) {
        float dtv = dtp[(size_t)t * DI];
        float hv  = hp[(size_t)t * DI];
        float Bv  = sp[(size_t)t * SSMW + DTR + s];
        float Cv  = sp[(size_t)t * SSMW + DTR + DS + s];
        float dA  = expf(dtv * Ads);
        state = dA * state + dtv * hv * Bv;
        float contrib = state * Cv;
        contrib += __shfl_xor(contrib, 1, 16);
        contrib += __shfl_xor(contrib, 2, 16);
        contrib += __shfl_xor(contrib, 4, 16);
        contrib += __shfl_xor(contrib, 8, 16);
        if (s == 0) {
            float gv = gp[(size_t)t * (2 * DI)];
            float sig = 1.f / (1.f + expf(-gv));
            yp[(size_t)t * DI] = (contrib + Dd * hv) * (gv * sig);
        }
    }
}

// ---------------------------------------------------------------------------
// Launch
// ---------------------------------------------------------------------------
extern "C" void kernel_launch(void* const* d_in, const int* in_sizes, int n_in,
                              void* d_out, int out_size, void* d_ws, size_t ws_size,
                              hipStream_t stream)
{
    const int*   ids        = (const int*)  d_in[0];
    const float* embed      = (const float*)d_in[1];
    const float* norm_f_w   = (const float*)d_in[2];
    const float* in_proj_w  = (const float*)d_in[3];
    const float* conv_w     = (const float*)d_in[4];
    const float* conv_b     = (const float*)d_in[5];
    const float* x_proj_w   = (const float*)d_in[6];
    const float* dt_proj_w  = (const float*)d_in[7];
    const float* dt_proj_b  = (const float*)d_in[8];
    const float* A_log      = (const float*)d_in[9];
    const float* D_skip     = (const float*)d_in[10];
    const float* out_proj_w = (const float*)d_in[11];
    const float* norm_w     = (const float*)d_in[12];
    float* out = (float*)d_out;

    // fp32 workspace region
    float* ws    = (float*)d_ws;
    float* h     = ws;
    float* xn    = h     + ROWS * DM;
    float* proj  = xn    + ROWS * DM;
    float* hconv = proj  + ROWS * 2 * DI;
    float* ssm   = hconv + ROWS * DI;
    float* dtb   = ssm   + ROWS * SSMW;
    float* yb    = dtb   + ROWS * DI;
    const size_t F32_FLOATS = (size_t)ROWS * (DM + DM + 2*DI + DI + SSMW + DI + DI);

    // bf16 split planes (embed LAST so tier-1 works with smaller ws)
    const size_t IPW_E = (size_t)NL * 2 * DI * DM;   // 9,437,184
    const size_t OPW_E = (size_t)NL * DM * DI;       // 4,718,592
    const size_t ACT_E = (size_t)ROWS * DI;          // 1,572,864 (max activation)
    const size_t EMB_E = (size_t)VOCAB_ * DM;        // 24,576,000
    unsigned short* u0   = (unsigned short*)(ws + F32_FLOATS);
    unsigned short* ipwh = u0;
    unsigned short* ipwl = ipwh + IPW_E;
    unsigned short* opwh = ipwl + IPW_E;
    unsigned short* opwl = opwh + OPW_E;
    unsigned short* acth = opwl + OPW_E;
    unsigned short* actl = acth + ACT_E;
    unsigned short* embh = actl + ACT_E;
    unsigned short* embl = embh + EMB_E;
    const size_t NEED_PROJ = F32_FLOATS*4 + 2*2*(IPW_E + OPW_E + ACT_E);
    const size_t NEED_HEAD = NEED_PROJ + 2*2*EMB_E;
    const bool mfma_proj = ws_size >= NEED_PROJ;
    const bool mfma_head = ws_size >= NEED_HEAD;

    gather_kernel<<<(ROWS * DM + 255) / 256, 256, 0, stream>>>(ids, embed, h, ROWS * DM);

    if (mfma_proj) {
        split_kernel<<<(int)(IPW_E/4 + 255)/256, 256, 0, stream>>>(in_proj_w,  ipwh, ipwl, (int)(IPW_E/4));
        split_kernel<<<(int)(OPW_E/4 + 255)/256, 256, 0, stream>>>(out_proj_w, opwh, opwl, (int)(OPW_E/4));
    }
    if (mfma_head) {
        split_kernel<<<(int)(EMB_E/4 + 255)/256, 256, 0, stream>>>(embed, embh, embl, (int)(EMB_E/4));
    }

    for (int i = 0; i < NL; ++i) {
        const float* ipw = in_proj_w  + (size_t)i * 2 * DI * DM;
        const float* cw  = conv_w     + (size_t)i * DI * DCONV;
        const float* cb  = conv_b     + (size_t)i * DI;
        const float* xpw = x_proj_w   + (size_t)i * SSMW * DI;
        const float* dpw = dt_proj_w  + (size_t)i * DI * DTR;
        const float* dpb = dt_proj_b  + (size_t)i * DI;
        const float* al  = A_log      + (size_t)i * DI * DS;
        const float* dsk = D_skip     + (size_t)i * DI;
        const float* opw = out_proj_w + (size_t)i * DM * DI;
        const float* nw  = norm_w     + (size_t)i * DM;

        rmsnorm_kernel<<<ROWS, 256, 0, stream>>>(h, nw, xn, DM);

        if (mfma_proj) {
            split_kernel<<<(ROWS*DM/4 + 255)/256, 256, 0, stream>>>(xn, acth, actl, ROWS*DM/4);
            gemm_mfma<0><<<dim3(ROWS/128, (2*DI)/128), 256, 0, stream>>>(
                acth, actl, DM, ipwh + (size_t)i*2*DI*DM, ipwl + (size_t)i*2*DI*DM, DM,
                proj, 2*DI, DM, nullptr);
        } else {
            gemm_tn<0><<<dim3(ROWS/64, (2*DI)/64), 256, 0, stream>>>(
                xn, DM, ipw, DM, proj, 2*DI, ROWS, 2*DI, DM, nullptr, nullptr);
        }

        conv_silu_kernel<<<(ROWS * DI + 255) / 256, 256, 0, stream>>>(proj, cw, cb, hconv);

        gemm_tn<0><<<dim3(ROWS / 64, (SSMW + 63) / 64), 256, 0, stream>>>(
            hconv, DI, xpw, DI, ssm, SSMW, ROWS, SSMW, DI, nullptr, nullptr);

        gemm_tn<1><<<dim3(ROWS / 64, DI / 64), 256, 0, stream>>>(
            ssm, SSMW, dpw, DTR, dtb, DI, ROWS, DI, DTR, dpb, nullptr);

        scan_kernel<<<BB * (DI / 16), 256, 0, stream>>>(dtb, hconv, ssm, proj, al, dsk, yb);

        if (mfma_proj) {
            split_kernel<<<(ROWS*DI/4 + 255)/256, 256, 0, stream>>>(yb, acth, actl, ROWS*DI/4);
            gemm_mfma<2><<<dim3(ROWS/128, DM/128), 256, 0, stream>>>(
                acth, actl, DI, opwh + (size_t)i*DM*DI, opwl + (size_t)i*DM*DI, DI,
                h, DM, DI, h);
        } else {
            gemm_tn<2><<<dim3(ROWS/64, DM/64), 256, 0, stream>>>(
                yb, DI, opw, DI, h, DM, ROWS, DM, DI, nullptr, h);
        }
    }

    rmsnorm_kernel<<<ROWS, 256, 0, stream>>>(h, norm_f_w, xn, DM);
    if (mfma_head) {
        split_kernel<<<(ROWS*DM/4 + 255)/256, 256, 0, stream>>>(xn, acth, actl, ROWS*DM/4);
        gemm_mfma<0><<<dim3(ROWS/128, VOCAB_/128), 256, 0, stream>>>(
            acth, actl, DM, embh, embl, DM, out, VOCAB_, DM, nullptr);
    } else {
        gemm_tn<0><<<dim3(ROWS/64, VOCAB_/64), 256, 0, stream>>>(
            xn, DM, embed, DM, out, VOCAB_, ROWS, VOCAB_, DM, nullptr, nullptr);
    }
}

// Round 4
// 2132.496 us; speedup vs baseline: 2.7323x; 1.6167x over previous
//
#include <hip/hip_runtime.h>
#include <hip/hip_bf16.h>
#include <math.h>

// Model dims (compile-time constants)
#define NL 4
#define DM 768
#define DI 1536
#define DS 16
#define DTR 48
#define DCONV 4
#define VOCAB_ 32000
#define BB 2
#define LL 512
#define ROWS (BB*LL)   // 1024
#define SSMW (DTR + 2*DS)  // 80
#define NC 32              // scan chunks
#define CL (LL/NC)         // 16 steps per chunk
#define NDB (DI/16)        // 96 d-blocks

typedef __bf16 bf16x8 __attribute__((ext_vector_type(8)));
typedef float f32x4 __attribute__((ext_vector_type(4)));

// ---------------------------------------------------------------------------
// fp32 -> bf16 split helpers (RNE)
// ---------------------------------------------------------------------------
__device__ __forceinline__ unsigned short f2bf(float f) {
    unsigned u = __float_as_uint(f);
    u = u + 0x7fffu + ((u >> 16) & 1u);
    return (unsigned short)(u >> 16);
}
__device__ __forceinline__ float bf2f(unsigned short b) {
    return __uint_as_float((unsigned)b << 16);
}

__global__ __launch_bounds__(256) void split_kernel(
    const float* __restrict__ x,
    unsigned short* __restrict__ hi, unsigned short* __restrict__ lo, int n4)
{
    int i = blockIdx.x * 256 + threadIdx.x;
    if (i >= n4) return;
    const float4 v = ((const float4*)x)[i];
    float vv[4] = {v.x, v.y, v.z, v.w};
    unsigned short hh[4], ll[4];
    #pragma unroll
    for (int j = 0; j < 4; j++) {
        hh[j] = f2bf(vv[j]);
        ll[j] = f2bf(vv[j] - bf2f(hh[j]));
    }
    ((ushort4*)hi)[i] = make_ushort4(hh[0], hh[1], hh[2], hh[3]);
    ((ushort4*)lo)[i] = make_ushort4(ll[0], ll[1], ll[2], ll[3]);
}

// ---------------------------------------------------------------------------
// global -> LDS 16B async copy
// ---------------------------------------------------------------------------
__device__ __forceinline__ void gld16(void* l, const void* g) {
    __builtin_amdgcn_global_load_lds(
        (const __attribute__((address_space(1))) void*)g,
        (__attribute__((address_space(3))) void*)l, 16, 0, 0);
}

// ---------------------------------------------------------------------------
// bf16x3 MFMA GEMM (hi*hi + hi*lo + lo*hi), 128x128 tile, BK=32, 4 waves.
// LDS swizzle: physical slot = slot ^ ((row>>1)&3); inverse applied on global
// source, swizzled read offsets (both-sides rule).
// ---------------------------------------------------------------------------
template<int EPI>
__global__ __launch_bounds__(256) void gemm_mfma(
    const unsigned short* __restrict__ Ahi, const unsigned short* __restrict__ Alo, int lda,
    const unsigned short* __restrict__ Bhi, const unsigned short* __restrict__ Blo, int ldb,
    float* __restrict__ C, int ldc, int K,
    const float* __restrict__ resid)
{
    __shared__ __align__(16) unsigned short sAh[128*32];
    __shared__ __align__(16) unsigned short sAl[128*32];
    __shared__ __align__(16) unsigned short sBh[128*32];
    __shared__ __align__(16) unsigned short sBl[128*32];

    const int tid  = threadIdx.x;
    const int lane = tid & 63;
    const int m0 = blockIdx.x * 128;
    const int n0 = blockIdx.y * 128;
    const int w  = tid >> 6;
    const int wr = (w >> 1) * 64;
    const int wc = (w & 1) * 64;

    f32x4 acc[4][4];
    #pragma unroll
    for (int i = 0; i < 4; i++)
        #pragma unroll
        for (int j = 0; j < 4; j++)
            acc[i][j] = (f32x4){0.f, 0.f, 0.f, 0.f};

    const int srow = tid >> 2;
    const int ps   = tid & 3;
    const int lsl  = ps ^ ((srow >> 1) & 3);

    int offA[4], offB[4];
    #pragma unroll
    for (int i = 0; i < 4; i++) {
        int ra = wr + i*16 + (lane & 15);
        int pa = (lane >> 4) ^ ((ra >> 1) & 3);
        offA[i] = ra*32 + pa*8;
        int rb = wc + i*16 + (lane & 15);
        int pb = (lane >> 4) ^ ((rb >> 1) & 3);
        offB[i] = rb*32 + pb*8;
    }

    for (int k0 = 0; k0 < K; k0 += 32) {
        const size_t a1 = (size_t)(m0 + srow)      * lda + k0 + lsl*8;
        const size_t a2 = (size_t)(m0 + 64 + srow) * lda + k0 + lsl*8;
        const size_t b1 = (size_t)(n0 + srow)      * ldb + k0 + lsl*8;
        const size_t b2 = (size_t)(n0 + 64 + srow) * ldb + k0 + lsl*8;
        gld16(&sAh[(size_t)tid*8],       Ahi + a1);
        gld16(&sAh[(size_t)(256+tid)*8], Ahi + a2);
        gld16(&sAl[(size_t)tid*8],       Alo + a1);
        gld16(&sAl[(size_t)(256+tid)*8], Alo + a2);
        gld16(&sBh[(size_t)tid*8],       Bhi + b1);
        gld16(&sBh[(size_t)(256+tid)*8], Bhi + b2);
        gld16(&sBl[(size_t)tid*8],       Blo + b1);
        gld16(&sBl[(size_t)(256+tid)*8], Blo + b2);
        __syncthreads();

        bf16x8 ah[4], al[4], bh[4], bl[4];
        #pragma unroll
        for (int i = 0; i < 4; i++) {
            ah[i] = *(const bf16x8*)&sAh[offA[i]];
            al[i] = *(const bf16x8*)&sAl[offA[i]];
            bh[i] = *(const bf16x8*)&sBh[offB[i]];
            bl[i] = *(const bf16x8*)&sBl[offB[i]];
        }
        #pragma unroll
        for (int i = 0; i < 4; i++)
            #pragma unroll
            for (int j = 0; j < 4; j++) {
                acc[i][j] = __builtin_amdgcn_mfma_f32_16x16x32_bf16(ah[i], bh[j], acc[i][j], 0, 0, 0);
                acc[i][j] = __builtin_amdgcn_mfma_f32_16x16x32_bf16(ah[i], bl[j], acc[i][j], 0, 0, 0);
                acc[i][j] = __builtin_amdgcn_mfma_f32_16x16x32_bf16(al[i], bh[j], acc[i][j], 0, 0, 0);
            }
        __syncthreads();
    }

    #pragma unroll
    for (int i = 0; i < 4; i++) {
        int rbase = m0 + wr + i*16 + (lane >> 4)*4;
        #pragma unroll
        for (int j = 0; j < 4; j++) {
            int col = n0 + wc + j*16 + (lane & 15);
            #pragma unroll
            for (int r = 0; r < 4; r++) {
                float v = acc[i][j][r];
                if (EPI == 2) v += resid[(size_t)(rbase + r)*ldc + col];
                C[(size_t)(rbase + r)*ldc + col] = v;
            }
        }
    }
}

// ---------------------------------------------------------------------------
// Embedding gather
// ---------------------------------------------------------------------------
__global__ __launch_bounds__(256) void gather_kernel(
    const int* __restrict__ ids, const float* __restrict__ embed,
    float* __restrict__ h, int n)
{
    int idx = blockIdx.x * 256 + threadIdx.x;
    if (idx >= n) return;
    int d = idx % DM;
    int tok = idx / DM;
    h[idx] = embed[(size_t)ids[tok] * DM + d];
}

// ---------------------------------------------------------------------------
// RMSNorm
// ---------------------------------------------------------------------------
__global__ __launch_bounds__(256) void rmsnorm_kernel(
    const float* __restrict__ x, const float* __restrict__ w,
    float* __restrict__ out, int D)
{
    int row = blockIdx.x;
    const float* xr = x + (size_t)row * D;
    float ss = 0.f;
    for (int i = threadIdx.x; i < D; i += 256) { float v = xr[i]; ss += v * v; }
    for (int o = 32; o >= 1; o >>= 1) ss += __shfl_xor(ss, o, 64);
    __shared__ float sbuf[4];
    int wid = threadIdx.x >> 6;
    if ((threadIdx.x & 63) == 0) sbuf[wid] = ss;
    __syncthreads();
    if (threadIdx.x == 0) {
        float t = sbuf[0] + sbuf[1] + sbuf[2] + sbuf[3];
        sbuf[0] = 1.0f / sqrtf(t / (float)D + 1e-5f);
    }
    __syncthreads();
    float scale = sbuf[0];
    for (int i = threadIdx.x; i < D; i += 256)
        out[(size_t)row * D + i] = xr[i] * scale * w[i];
}

// ---------------------------------------------------------------------------
// fp32 GEMM (x_proj / dt_proj)
// ---------------------------------------------------------------------------
template<int EPI>
__global__ __launch_bounds__(256) void gemm_tn(
    const float* __restrict__ A, int lda,
    const float* __restrict__ W, int ldw,
    float* __restrict__ C, int ldc,
    int M, int N, int K,
    const float* __restrict__ bias,
    const float* __restrict__ resid)
{
    const int tid = threadIdx.x;
    const int tx = tid & 15;
    const int ty = tid >> 4;
    const int m0 = blockIdx.x * 64;
    const int n0 = blockIdx.y * 64;

    __shared__ float As[16][65];
    __shared__ float Ws[16][65];

    float acc[4][4];
    #pragma unroll
    for (int i = 0; i < 4; i++)
        #pragma unroll
        for (int j = 0; j < 4; j++) acc[i][j] = 0.f;

    const int lrow = tid >> 2;
    const int lk   = (tid & 3) * 4;

    for (int k0 = 0; k0 < K; k0 += 16) {
        {
            int m = m0 + lrow;
            int n = n0 + lrow;
            #pragma unroll
            for (int j = 0; j < 4; j++) {
                int k = k0 + lk + j;
                As[lk + j][lrow] = (m < M && k < K) ? A[(size_t)m * lda + k] : 0.f;
                Ws[lk + j][lrow] = (n < N && k < K) ? W[(size_t)n * ldw + k] : 0.f;
            }
        }
        __syncthreads();
        #pragma unroll
        for (int k = 0; k < 16; k++) {
            float a[4], wv[4];
            #pragma unroll
            for (int i = 0; i < 4; i++) a[i] = As[k][ty * 4 + i];
            #pragma unroll
            for (int j = 0; j < 4; j++) wv[j] = Ws[k][tx * 4 + j];
            #pragma unroll
            for (int i = 0; i < 4; i++)
                #pragma unroll
                for (int j = 0; j < 4; j++)
                    acc[i][j] += a[i] * wv[j];
        }
        __syncthreads();
    }

    #pragma unroll
    for (int i = 0; i < 4; i++) {
        int m = m0 + ty * 4 + i;
        if (m >= M) continue;
        #pragma unroll
        for (int j = 0; j < 4; j++) {
            int n = n0 + tx * 4 + j;
            if (n >= N) continue;
            float v = acc[i][j];
            if (EPI == 1) {
                v += bias[n];
                v = fmaxf(v, 0.f) + log1pf(expf(-fabsf(v)));
            }
            if (EPI == 2) v += resid[(size_t)m * ldc + n];
            C[(size_t)m * ldc + n] = v;
        }
    }
}

// ---------------------------------------------------------------------------
// Causal depthwise conv (k=4) + SiLU
// ---------------------------------------------------------------------------
__global__ __launch_bounds__(256) void conv_silu_kernel(
    const float* __restrict__ proj,
    const float* __restrict__ cw, const float* __restrict__ cb,
    float* __restrict__ hconv)
{
    int idx = blockIdx.x * 256 + threadIdx.x;
    if (idx >= ROWS * DI) return;
    int d = idx % DI;
    int bt = idx / DI;
    int t = bt % LL;
    float sum = cb[d];
    #pragma unroll
    for (int j = 0; j < DCONV; j++) {
        int tt = t - (DCONV - 1) + j;
        if (tt >= 0)
            sum += cw[d * DCONV + j] * proj[(size_t)(bt - (DCONV - 1) + j) * (2 * DI) + d];
    }
    float sig = 1.f / (1.f + expf(-sum));
    hconv[idx] = sum * sig;
}

// ---------------------------------------------------------------------------
// Chunked selective scan — pass 1: per-chunk local scan.
// Grid: BB*NC*NDB blocks of 256 (16 d-groups x 16 s-lanes).
// Writes raw y_local (no gate/skip), chunk end-state E, chunk decay P.
// ---------------------------------------------------------------------------
__global__ __launch_bounds__(256) void scan_local_kernel(
    const float* __restrict__ dt, const float* __restrict__ hconv,
    const float* __restrict__ ssm, const float* __restrict__ A_log,
    float* __restrict__ ylocal, float* __restrict__ E, float* __restrict__ P)
{
    const int tid = threadIdx.x;
    const int s  = tid & 15;
    const int dg = tid >> 4;
    int blk = blockIdx.x;
    const int dblk = blk % NDB; blk /= NDB;
    const int c = blk % NC;
    const int b = blk / NC;
    const int d = dblk * 16 + dg;

    const float Ads = -expf(A_log[(size_t)d * DS + s]);
    float state = 0.f, Ssum = 0.f;
    const int t0 = c * CL;
    const float* dtp = dt     + ((size_t)b*LL + t0)*DI + d;
    const float* hp  = hconv  + ((size_t)b*LL + t0)*DI + d;
    const float* sp  = ssm    + ((size_t)b*LL + t0)*SSMW;
    float*       yp  = ylocal + ((size_t)b*LL + t0)*DI + d;

    for (int t = 0; t < CL; ++t) {
        float dtv = dtp[(size_t)t * DI];
        float hv  = hp[(size_t)t * DI];
        float Bv  = sp[(size_t)t * SSMW + DTR + s];
        float Cv  = sp[(size_t)t * SSMW + DTR + DS + s];
        float dA  = expf(dtv * Ads);
        state = dA * state + dtv * hv * Bv;
        Ssum += dtv;
        float contrib = state * Cv;
        contrib += __shfl_xor(contrib, 1, 16);
        contrib += __shfl_xor(contrib, 2, 16);
        contrib += __shfl_xor(contrib, 4, 16);
        contrib += __shfl_xor(contrib, 8, 16);
        if (s == 0) yp[(size_t)t * DI] = contrib;
    }
    const size_t si = (((size_t)b*NC + c)*DI + d)*DS + s;
    E[si] = state;
    P[si] = expf(Ads * Ssum);
}

// ---------------------------------------------------------------------------
// Pass 2: carry combine. carry[c] = P[c-1]*carry[c-1] + E[c-1], carry[0]=0.
// Parallel over BB*DI*DS elements, serial over NC.
// ---------------------------------------------------------------------------
__global__ __launch_bounds__(256) void scan_carry_kernel(
    const float* __restrict__ E, const float* __restrict__ P,
    float* __restrict__ carry)
{
    int g = blockIdx.x * 256 + threadIdx.x;
    if (g >= BB * DI * DS) return;
    int b   = g / (DI * DS);
    int dsi = g % (DI * DS);
    float cv = 0.f;
    for (int c = 0; c < NC; ++c) {
        size_t idx = ((size_t)b*NC + c)*(DI*DS) + dsi;
        carry[idx] = cv;
        cv = P[idx] * cv + E[idx];
    }
}

// ---------------------------------------------------------------------------
// Pass 3: fix-up + epilogue. y = (y_local + sum_s exp(A*S_t)*carry*C + D*h) * silu(gate)
// ---------------------------------------------------------------------------
__global__ __launch_bounds__(256) void scan_fix_kernel(
    const float* __restrict__ dt, const float* __restrict__ hconv,
    const float* __restrict__ ssm, const float* __restrict__ proj,
    const float* __restrict__ A_log, const float* __restrict__ D_skip,
    const float* __restrict__ carry, float* __restrict__ y)
{
    const int tid = threadIdx.x;
    const int s  = tid & 15;
    const int dg = tid >> 4;
    int blk = blockIdx.x;
    const int dblk = blk % NDB; blk /= NDB;
    const int c = blk % NC;
    const int b = blk / NC;
    const int d = dblk * 16 + dg;

    const float Ads = -expf(A_log[(size_t)d * DS + s]);
    const float Dd  = D_skip[d];
    const float cv  = carry[(((size_t)b*NC + c)*DI + d)*DS + s];
    float S = 0.f;
    const int t0 = c * CL;
    const float* dtp = dt    + ((size_t)b*LL + t0)*DI + d;
    const float* hp  = hconv + ((size_t)b*LL + t0)*DI + d;
    const float* sp  = ssm   + ((size_t)b*LL + t0)*SSMW;
    const float* gp  = proj  + ((size_t)b*LL + t0)*(2*DI) + DI + d;
    float*       yp  = y     + ((size_t)b*LL + t0)*DI + d;

    for (int t = 0; t < CL; ++t) {
        float dtv = dtp[(size_t)t * DI];
        S += dtv;
        float Cv = sp[(size_t)t * SSMW + DTR + DS + s];
        float contrib = expf(Ads * S) * cv * Cv;
        contrib += __shfl_xor(contrib, 1, 16);
        contrib += __shfl_xor(contrib, 2, 16);
        contrib += __shfl_xor(contrib, 4, 16);
        contrib += __shfl_xor(contrib, 8, 16);
        if (s == 0) {
            float hv  = hp[(size_t)t * DI];
            float ylo = yp[(size_t)t * DI];
            float gv  = gp[(size_t)t * (2*DI)];
            float sig = 1.f / (1.f + expf(-gv));
            yp[(size_t)t * DI] = (ylo + contrib + Dd * hv) * (gv * sig);
        }
    }
}

// ---------------------------------------------------------------------------
// Launch
// ---------------------------------------------------------------------------
extern "C" void kernel_launch(void* const* d_in, const int* in_sizes, int n_in,
                              void* d_out, int out_size, void* d_ws, size_t ws_size,
                              hipStream_t stream)
{
    const int*   ids        = (const int*)  d_in[0];
    const float* embed      = (const float*)d_in[1];
    const float* norm_f_w   = (const float*)d_in[2];
    const float* in_proj_w  = (const float*)d_in[3];
    const float* conv_w     = (const float*)d_in[4];
    const float* conv_b     = (const float*)d_in[5];
    const float* x_proj_w   = (const float*)d_in[6];
    const float* dt_proj_w  = (const float*)d_in[7];
    const float* dt_proj_b  = (const float*)d_in[8];
    const float* A_log      = (const float*)d_in[9];
    const float* D_skip     = (const float*)d_in[10];
    const float* out_proj_w = (const float*)d_in[11];
    const float* norm_w     = (const float*)d_in[12];
    float* out = (float*)d_out;

    // fp32 workspace region
    float* ws    = (float*)d_ws;
    float* h     = ws;
    float* xn    = h     + ROWS * DM;
    float* proj  = xn    + ROWS * DM;
    float* hconv = proj  + ROWS * 2 * DI;
    float* ssm   = hconv + ROWS * DI;
    float* dtb   = ssm   + ROWS * SSMW;
    float* yb    = dtb   + ROWS * DI;
    float* Ebuf  = yb    + ROWS * DI;          // [BB,NC,DI,DS] = ROWS*DI floats
    float* Pbuf  = Ebuf  + (size_t)BB*NC*DI*DS;
    float* cbuf  = Pbuf  + (size_t)BB*NC*DI*DS;
    const size_t F32_FLOATS = (size_t)ROWS * (DM + DM + 2*DI + DI + SSMW + DI + DI)
                            + 3 * (size_t)BB*NC*DI*DS;

    // bf16 split planes (embed LAST so tier-1 works with smaller ws)
    const size_t IPW_E = (size_t)NL * 2 * DI * DM;
    const size_t OPW_E = (size_t)NL * DM * DI;
    const size_t ACT_E = (size_t)ROWS * DI;
    const size_t EMB_E = (size_t)VOCAB_ * DM;
    unsigned short* u0   = (unsigned short*)(ws + F32_FLOATS);
    unsigned short* ipwh = u0;
    unsigned short* ipwl = ipwh + IPW_E;
    unsigned short* opwh = ipwl + IPW_E;
    unsigned short* opwl = opwh + OPW_E;
    unsigned short* acth = opwl + OPW_E;
    unsigned short* actl = acth + ACT_E;
    unsigned short* embh = actl + ACT_E;
    unsigned short* embl = embh + EMB_E;
    const size_t NEED_PROJ = F32_FLOATS*4 + 2*2*(IPW_E + OPW_E + ACT_E);
    const size_t NEED_HEAD = NEED_PROJ + 2*2*EMB_E;
    const bool mfma_proj = ws_size >= NEED_PROJ;
    const bool mfma_head = ws_size >= NEED_HEAD;

    gather_kernel<<<(ROWS * DM + 255) / 256, 256, 0, stream>>>(ids, embed, h, ROWS * DM);

    if (mfma_proj) {
        split_kernel<<<(int)(IPW_E/4 + 255)/256, 256, 0, stream>>>(in_proj_w,  ipwh, ipwl, (int)(IPW_E/4));
        split_kernel<<<(int)(OPW_E/4 + 255)/256, 256, 0, stream>>>(out_proj_w, opwh, opwl, (int)(OPW_E/4));
    }
    if (mfma_head) {
        split_kernel<<<(int)(EMB_E/4 + 255)/256, 256, 0, stream>>>(embed, embh, embl, (int)(EMB_E/4));
    }

    for (int i = 0; i < NL; ++i) {
        const float* ipw = in_proj_w  + (size_t)i * 2 * DI * DM;
        const float* cw  = conv_w     + (size_t)i * DI * DCONV;
        const float* cb  = conv_b     + (size_t)i * DI;
        const float* xpw = x_proj_w   + (size_t)i * SSMW * DI;
        const float* dpw = dt_proj_w  + (size_t)i * DI * DTR;
        const float* dpb = dt_proj_b  + (size_t)i * DI;
        const float* al  = A_log      + (size_t)i * DI * DS;
        const float* dsk = D_skip     + (size_t)i * DI;
        const float* opw = out_proj_w + (size_t)i * DM * DI;
        const float* nw  = norm_w     + (size_t)i * DM;

        rmsnorm_kernel<<<ROWS, 256, 0, stream>>>(h, nw, xn, DM);

        if (mfma_proj) {
            split_kernel<<<(ROWS*DM/4 + 255)/256, 256, 0, stream>>>(xn, acth, actl, ROWS*DM/4);
            gemm_mfma<0><<<dim3(ROWS/128, (2*DI)/128), 256, 0, stream>>>(
                acth, actl, DM, ipwh + (size_t)i*2*DI*DM, ipwl + (size_t)i*2*DI*DM, DM,
                proj, 2*DI, DM, nullptr);
        } else {
            gemm_tn<0><<<dim3(ROWS/64, (2*DI)/64), 256, 0, stream>>>(
                xn, DM, ipw, DM, proj, 2*DI, ROWS, 2*DI, DM, nullptr, nullptr);
        }

        conv_silu_kernel<<<(ROWS * DI + 255) / 256, 256, 0, stream>>>(proj, cw, cb, hconv);

        gemm_tn<0><<<dim3(ROWS / 64, (SSMW + 63) / 64), 256, 0, stream>>>(
            hconv, DI, xpw, DI, ssm, SSMW, ROWS, SSMW, DI, nullptr, nullptr);

        gemm_tn<1><<<dim3(ROWS / 64, DI / 64), 256, 0, stream>>>(
            ssm, SSMW, dpw, DTR, dtb, DI, ROWS, DI, DTR, dpb, nullptr);

        // chunked scan: local -> carry -> fix
        scan_local_kernel<<<BB*NC*NDB, 256, 0, stream>>>(dtb, hconv, ssm, al, yb, Ebuf, Pbuf);
        scan_carry_kernel<<<(BB*DI*DS + 255)/256, 256, 0, stream>>>(Ebuf, Pbuf, cbuf);
        scan_fix_kernel<<<BB*NC*NDB, 256, 0, stream>>>(dtb, hconv, ssm, proj, al, dsk, cbuf, yb);

        if (mfma_proj) {
            split_kernel<<<(ROWS*DI/4 + 255)/256, 256, 0, stream>>>(yb, acth, actl, ROWS*DI/4);
            gemm_mfma<2><<<dim3(ROWS/128, DM/128), 256, 0, stream>>>(
                acth, actl, DI, opwh + (size_t)i*DM*DI, opwl + (size_t)i*DM*DI, DI,
                h, DM, DI, h);
        } else {
            gemm_tn<2><<<dim3(ROWS/64, DM/64), 256, 0, stream>>>(
                yb, DI, opw, DI, h, DM, ROWS, DM, DI, nullptr, h);
        }
    }

    rmsnorm_kernel<<<ROWS, 256, 0, stream>>>(h, norm_f_w, xn, DM);
    if (mfma_head) {
        split_kernel<<<(ROWS*DM/4 + 255)/256, 256, 0, stream>>>(xn, acth, actl, ROWS*DM/4);
        gemm_mfma<0><<<dim3(ROWS/128, VOCAB_/128), 256, 0, stream>>>(
            acth, actl, DM, embh, embl, DM, out, VOCAB_, DM, nullptr);
    } else {
        gemm_tn<0><<<dim3(ROWS/64, VOCAB_/64), 256, 0, stream>>>(
            xn, DM, embed, DM, out, VOCAB_, ROWS, VOCAB_, DM, nullptr, nullptr);
    }
}

// Round 5
// 1433.569 us; speedup vs baseline: 4.0644x; 1.4875x over previous
//
#include <hip/hip_runtime.h>
#include <hip/hip_bf16.h>
#include <math.h>

// Model dims (compile-time constants)
#define NL 4
#define DM 768
#define DI 1536
#define DS 16
#define DTR 48
#define DCONV 4
#define VOCAB_ 32000
#define BB 2
#define LL 512
#define ROWS (BB*LL)   // 1024
#define SSMW (DTR + 2*DS)  // 80
#define NC 32              // scan chunks
#define CL (LL/NC)         // 16 steps per chunk
#define NDB (DI/16)        // 96 d-blocks
#define XP_KS 16           // x_proj split-K factor
#define XP_KC (DI/XP_KS)   // 96

typedef __bf16 bf16x8 __attribute__((ext_vector_type(8)));
typedef float f32x4 __attribute__((ext_vector_type(4)));

// ---------------------------------------------------------------------------
// fp32 -> bf16 split helpers (RNE)
// ---------------------------------------------------------------------------
__device__ __forceinline__ unsigned short f2bf(float f) {
    unsigned u = __float_as_uint(f);
    u = u + 0x7fffu + ((u >> 16) & 1u);
    return (unsigned short)(u >> 16);
}
__device__ __forceinline__ float bf2f(unsigned short b) {
    return __uint_as_float((unsigned)b << 16);
}

__global__ __launch_bounds__(256) void split_kernel(
    const float* __restrict__ x,
    unsigned short* __restrict__ hi, unsigned short* __restrict__ lo, int n4)
{
    int i = blockIdx.x * 256 + threadIdx.x;
    if (i >= n4) return;
    const float4 v = ((const float4*)x)[i];
    float vv[4] = {v.x, v.y, v.z, v.w};
    unsigned short hh[4], ll[4];
    #pragma unroll
    for (int j = 0; j < 4; j++) {
        hh[j] = f2bf(vv[j]);
        ll[j] = f2bf(vv[j] - bf2f(hh[j]));
    }
    ((ushort4*)hi)[i] = make_ushort4(hh[0], hh[1], hh[2], hh[3]);
    ((ushort4*)lo)[i] = make_ushort4(ll[0], ll[1], ll[2], ll[3]);
}

// ---------------------------------------------------------------------------
// global -> LDS 16B async copy
// ---------------------------------------------------------------------------
__device__ __forceinline__ void gld16(void* l, const void* g) {
    __builtin_amdgcn_global_load_lds(
        (const __attribute__((address_space(1))) void*)g,
        (__attribute__((address_space(3))) void*)l, 16, 0, 0);
}

// ---------------------------------------------------------------------------
// bf16x3 MFMA GEMM (hi*hi + hi*lo + lo*hi), 128x128 tile, BK=32, 4 waves.
// ---------------------------------------------------------------------------
template<int EPI>
__global__ __launch_bounds__(256) void gemm_mfma(
    const unsigned short* __restrict__ Ahi, const unsigned short* __restrict__ Alo, int lda,
    const unsigned short* __restrict__ Bhi, const unsigned short* __restrict__ Blo, int ldb,
    float* __restrict__ C, int ldc, int K,
    const float* __restrict__ resid)
{
    __shared__ __align__(16) unsigned short sAh[128*32];
    __shared__ __align__(16) unsigned short sAl[128*32];
    __shared__ __align__(16) unsigned short sBh[128*32];
    __shared__ __align__(16) unsigned short sBl[128*32];

    const int tid  = threadIdx.x;
    const int lane = tid & 63;
    const int m0 = blockIdx.x * 128;
    const int n0 = blockIdx.y * 128;
    const int w  = tid >> 6;
    const int wr = (w >> 1) * 64;
    const int wc = (w & 1) * 64;

    f32x4 acc[4][4];
    #pragma unroll
    for (int i = 0; i < 4; i++)
        #pragma unroll
        for (int j = 0; j < 4; j++)
            acc[i][j] = (f32x4){0.f, 0.f, 0.f, 0.f};

    const int srow = tid >> 2;
    const int ps   = tid & 3;
    const int lsl  = ps ^ ((srow >> 1) & 3);

    int offA[4], offB[4];
    #pragma unroll
    for (int i = 0; i < 4; i++) {
        int ra = wr + i*16 + (lane & 15);
        int pa = (lane >> 4) ^ ((ra >> 1) & 3);
        offA[i] = ra*32 + pa*8;
        int rb = wc + i*16 + (lane & 15);
        int pb = (lane >> 4) ^ ((rb >> 1) & 3);
        offB[i] = rb*32 + pb*8;
    }

    for (int k0 = 0; k0 < K; k0 += 32) {
        const size_t a1 = (size_t)(m0 + srow)      * lda + k0 + lsl*8;
        const size_t a2 = (size_t)(m0 + 64 + srow) * lda + k0 + lsl*8;
        const size_t b1 = (size_t)(n0 + srow)      * ldb + k0 + lsl*8;
        const size_t b2 = (size_t)(n0 + 64 + srow) * ldb + k0 + lsl*8;
        gld16(&sAh[(size_t)tid*8],       Ahi + a1);
        gld16(&sAh[(size_t)(256+tid)*8], Ahi + a2);
        gld16(&sAl[(size_t)tid*8],       Alo + a1);
        gld16(&sAl[(size_t)(256+tid)*8], Alo + a2);
        gld16(&sBh[(size_t)tid*8],       Bhi + b1);
        gld16(&sBh[(size_t)(256+tid)*8], Bhi + b2);
        gld16(&sBl[(size_t)tid*8],       Blo + b1);
        gld16(&sBl[(size_t)(256+tid)*8], Blo + b2);
        __syncthreads();

        bf16x8 ah[4], al[4], bh[4], bl[4];
        #pragma unroll
        for (int i = 0; i < 4; i++) {
            ah[i] = *(const bf16x8*)&sAh[offA[i]];
            al[i] = *(const bf16x8*)&sAl[offA[i]];
            bh[i] = *(const bf16x8*)&sBh[offB[i]];
            bl[i] = *(const bf16x8*)&sBl[offB[i]];
        }
        #pragma unroll
        for (int i = 0; i < 4; i++)
            #pragma unroll
            for (int j = 0; j < 4; j++) {
                acc[i][j] = __builtin_amdgcn_mfma_f32_16x16x32_bf16(ah[i], bh[j], acc[i][j], 0, 0, 0);
                acc[i][j] = __builtin_amdgcn_mfma_f32_16x16x32_bf16(ah[i], bl[j], acc[i][j], 0, 0, 0);
                acc[i][j] = __builtin_amdgcn_mfma_f32_16x16x32_bf16(al[i], bh[j], acc[i][j], 0, 0, 0);
            }
        __syncthreads();
    }

    #pragma unroll
    for (int i = 0; i < 4; i++) {
        int rbase = m0 + wr + i*16 + (lane >> 4)*4;
        #pragma unroll
        for (int j = 0; j < 4; j++) {
            int col = n0 + wc + j*16 + (lane & 15);
            #pragma unroll
            for (int r = 0; r < 4; r++) {
                float v = acc[i][j][r];
                if (EPI == 2) v += resid[(size_t)(rbase + r)*ldc + col];
                C[(size_t)(rbase + r)*ldc + col] = v;
            }
        }
    }
}

// ---------------------------------------------------------------------------
// Embedding gather
// ---------------------------------------------------------------------------
__global__ __launch_bounds__(256) void gather_kernel(
    const int* __restrict__ ids, const float* __restrict__ embed,
    float* __restrict__ h, int n)
{
    int idx = blockIdx.x * 256 + threadIdx.x;
    if (idx >= n) return;
    int d = idx % DM;
    int tok = idx / DM;
    h[idx] = embed[(size_t)ids[tok] * DM + d];
}

// ---------------------------------------------------------------------------
// RMSNorm
// ---------------------------------------------------------------------------
__global__ __launch_bounds__(256) void rmsnorm_kernel(
    const float* __restrict__ x, const float* __restrict__ w,
    float* __restrict__ out, int D)
{
    int row = blockIdx.x;
    const float* xr = x + (size_t)row * D;
    float ss = 0.f;
    for (int i = threadIdx.x; i < D; i += 256) { float v = xr[i]; ss += v * v; }
    for (int o = 32; o >= 1; o >>= 1) ss += __shfl_xor(ss, o, 64);
    __shared__ float sbuf[4];
    int wid = threadIdx.x >> 6;
    if ((threadIdx.x & 63) == 0) sbuf[wid] = ss;
    __syncthreads();
    if (threadIdx.x == 0) {
        float t = sbuf[0] + sbuf[1] + sbuf[2] + sbuf[3];
        sbuf[0] = 1.0f / sqrtf(t / (float)D + 1e-5f);
    }
    __syncthreads();
    float scale = sbuf[0];
    for (int i = threadIdx.x; i < D; i += 256)
        out[(size_t)row * D + i] = xr[i] * scale * w[i];
}

// ---------------------------------------------------------------------------
// fp32 GEMM (dt_proj and fallback)
// ---------------------------------------------------------------------------
template<int EPI>
__global__ __launch_bounds__(256) void gemm_tn(
    const float* __restrict__ A, int lda,
    const float* __restrict__ W, int ldw,
    float* __restrict__ C, int ldc,
    int M, int N, int K,
    const float* __restrict__ bias,
    const float* __restrict__ resid)
{
    const int tid = threadIdx.x;
    const int tx = tid & 15;
    const int ty = tid >> 4;
    const int m0 = blockIdx.x * 64;
    const int n0 = blockIdx.y * 64;

    __shared__ float As[16][65];
    __shared__ float Ws[16][65];

    float acc[4][4];
    #pragma unroll
    for (int i = 0; i < 4; i++)
        #pragma unroll
        for (int j = 0; j < 4; j++) acc[i][j] = 0.f;

    const int lrow = tid >> 2;
    const int lk   = (tid & 3) * 4;

    for (int k0 = 0; k0 < K; k0 += 16) {
        {
            int m = m0 + lrow;
            int n = n0 + lrow;
            #pragma unroll
            for (int j = 0; j < 4; j++) {
                int k = k0 + lk + j;
                As[lk + j][lrow] = (m < M && k < K) ? A[(size_t)m * lda + k] : 0.f;
                Ws[lk + j][lrow] = (n < N && k < K) ? W[(size_t)n * ldw + k] : 0.f;
            }
        }
        __syncthreads();
        #pragma unroll
        for (int k = 0; k < 16; k++) {
            float a[4], wv[4];
            #pragma unroll
            for (int i = 0; i < 4; i++) a[i] = As[k][ty * 4 + i];
            #pragma unroll
            for (int j = 0; j < 4; j++) wv[j] = Ws[k][tx * 4 + j];
            #pragma unroll
            for (int i = 0; i < 4; i++)
                #pragma unroll
                for (int j = 0; j < 4; j++)
                    acc[i][j] += a[i] * wv[j];
        }
        __syncthreads();
    }

    #pragma unroll
    for (int i = 0; i < 4; i++) {
        int m = m0 + ty * 4 + i;
        if (m >= M) continue;
        #pragma unroll
        for (int j = 0; j < 4; j++) {
            int n = n0 + tx * 4 + j;
            if (n >= N) continue;
            float v = acc[i][j];
            if (EPI == 1) {
                v += bias[n];
                v = fmaxf(v, 0.f) + log1pf(expf(-fabsf(v)));
            }
            if (EPI == 2) v += resid[(size_t)m * ldc + n];
            C[(size_t)m * ldc + n] = v;
        }
    }
}

// ---------------------------------------------------------------------------
// x_proj split-K skinny GEMM: part[ks][M][80] = A[M, ks*96 : +96] @ W[:, ...]^T
// Grid: (ROWS/32, XP_KS), 256 threads, 2x5 microtile.
// LDS rows padded to 97 (bank-conflict-free: A broadcast/stride-2-banks,
// W stride 5 mod 32, gcd(5,32)=1).
// ---------------------------------------------------------------------------
__global__ __launch_bounds__(256) void xproj_partial_kernel(
    const float* __restrict__ A,    // hconv [ROWS, DI]
    const float* __restrict__ W,    // x_proj_w [SSMW, DI]
    float* __restrict__ part)       // [XP_KS, ROWS, SSMW]
{
    __shared__ float sA[32*97];
    __shared__ float sW[80*97];
    const int m0 = blockIdx.x * 32;
    const int k0 = blockIdx.y * XP_KC;

    for (int idx = threadIdx.x; idx < 32*XP_KC; idx += 256) {
        int r = idx / XP_KC, k = idx % XP_KC;
        sA[r*97 + k] = A[(size_t)(m0 + r)*DI + k0 + k];
    }
    for (int idx = threadIdx.x; idx < 80*XP_KC; idx += 256) {
        int r = idx / XP_KC, k = idx % XP_KC;
        sW[r*97 + k] = W[(size_t)r*DI + k0 + k];
    }
    __syncthreads();

    const int tr = (threadIdx.x >> 4) * 2;   // 0..30
    const int tc = (threadIdx.x & 15) * 5;   // 0..75
    float acc[2][5];
    #pragma unroll
    for (int i = 0; i < 2; i++)
        #pragma unroll
        for (int j = 0; j < 5; j++) acc[i][j] = 0.f;

    #pragma unroll 4
    for (int k = 0; k < XP_KC; ++k) {
        float a0 = sA[tr*97 + k];
        float a1 = sA[(tr+1)*97 + k];
        float w0 = sW[(tc+0)*97 + k];
        float w1 = sW[(tc+1)*97 + k];
        float w2 = sW[(tc+2)*97 + k];
        float w3 = sW[(tc+3)*97 + k];
        float w4 = sW[(tc+4)*97 + k];
        acc[0][0] += a0*w0; acc[0][1] += a0*w1; acc[0][2] += a0*w2;
        acc[0][3] += a0*w3; acc[0][4] += a0*w4;
        acc[1][0] += a1*w0; acc[1][1] += a1*w1; acc[1][2] += a1*w2;
        acc[1][3] += a1*w3; acc[1][4] += a1*w4;
    }

    float* pp = part + ((size_t)blockIdx.y * ROWS + m0) * SSMW;
    #pragma unroll
    for (int i = 0; i < 2; i++)
        #pragma unroll
        for (int j = 0; j < 5; j++)
            pp[(size_t)(tr + i)*SSMW + tc + j] = acc[i][j];
}

__global__ __launch_bounds__(256) void xproj_reduce_kernel(
    const float* __restrict__ part, float* __restrict__ ssmout)
{
    int i = blockIdx.x * 256 + threadIdx.x;
    if (i >= ROWS * SSMW) return;
    float s = 0.f;
    #pragma unroll
    for (int ks = 0; ks < XP_KS; ++ks)
        s += part[(size_t)ks * ROWS * SSMW + i];
    ssmout[i] = s;
}

// ---------------------------------------------------------------------------
// Causal depthwise conv (k=4) + SiLU
// ---------------------------------------------------------------------------
__global__ __launch_bounds__(256) void conv_silu_kernel(
    const float* __restrict__ proj,
    const float* __restrict__ cw, const float* __restrict__ cb,
    float* __restrict__ hconv)
{
    int idx = blockIdx.x * 256 + threadIdx.x;
    if (idx >= ROWS * DI) return;
    int d = idx % DI;
    int bt = idx / DI;
    int t = bt % LL;
    float sum = cb[d];
    #pragma unroll
    for (int j = 0; j < DCONV; j++) {
        int tt = t - (DCONV - 1) + j;
        if (tt >= 0)
            sum += cw[d * DCONV + j] * proj[(size_t)(bt - (DCONV - 1) + j) * (2 * DI) + d];
    }
    float sig = 1.f / (1.f + expf(-sum));
    hconv[idx] = sum * sig;
}

// ---------------------------------------------------------------------------
// Chunked selective scan — pass 1: per-chunk local scan
// ---------------------------------------------------------------------------
__global__ __launch_bounds__(256) void scan_local_kernel(
    const float* __restrict__ dt, const float* __restrict__ hconv,
    const float* __restrict__ ssm, const float* __restrict__ A_log,
    float* __restrict__ ylocal, float* __restrict__ E, float* __restrict__ P)
{
    const int tid = threadIdx.x;
    const int s  = tid & 15;
    const int dg = tid >> 4;
    int blk = blockIdx.x;
    const int dblk = blk % NDB; blk /= NDB;
    const int c = blk % NC;
    const int b = blk / NC;
    const int d = dblk * 16 + dg;

    const float Ads = -expf(A_log[(size_t)d * DS + s]);
    float state = 0.f, Ssum = 0.f;
    const int t0 = c * CL;
    const float* dtp = dt     + ((size_t)b*LL + t0)*DI + d;
    const float* hp  = hconv  + ((size_t)b*LL + t0)*DI + d;
    const float* sp  = ssm    + ((size_t)b*LL + t0)*SSMW;
    float*       yp  = ylocal + ((size_t)b*LL + t0)*DI + d;

    for (int t = 0; t < CL; ++t) {
        float dtv = dtp[(size_t)t * DI];
        float hv  = hp[(size_t)t * DI];
        float Bv  = sp[(size_t)t * SSMW + DTR + s];
        float Cv  = sp[(size_t)t * SSMW + DTR + DS + s];
        float dA  = expf(dtv * Ads);
        state = dA * state + dtv * hv * Bv;
        Ssum += dtv;
        float contrib = state * Cv;
        contrib += __shfl_xor(contrib, 1, 16);
        contrib += __shfl_xor(contrib, 2, 16);
        contrib += __shfl_xor(contrib, 4, 16);
        contrib += __shfl_xor(contrib, 8, 16);
        if (s == 0) yp[(size_t)t * DI] = contrib;
    }
    const size_t si = (((size_t)b*NC + c)*DI + d)*DS + s;
    E[si] = state;
    P[si] = expf(Ads * Ssum);
}

// ---------------------------------------------------------------------------
// Pass 2: carry combine
// ---------------------------------------------------------------------------
__global__ __launch_bounds__(256) void scan_carry_kernel(
    const float* __restrict__ E, const float* __restrict__ P,
    float* __restrict__ carry)
{
    int g = blockIdx.x * 256 + threadIdx.x;
    if (g >= BB * DI * DS) return;
    int b   = g / (DI * DS);
    int dsi = g % (DI * DS);
    float cv = 0.f;
    for (int c = 0; c < NC; ++c) {
        size_t idx = ((size_t)b*NC + c)*(DI*DS) + dsi;
        carry[idx] = cv;
        cv = P[idx] * cv + E[idx];
    }
}

// ---------------------------------------------------------------------------
// Pass 3: fix-up + epilogue
// ---------------------------------------------------------------------------
__global__ __launch_bounds__(256) void scan_fix_kernel(
    const float* __restrict__ dt, const float* __restrict__ hconv,
    const float* __restrict__ ssm, const float* __restrict__ proj,
    const float* __restrict__ A_log, const float* __restrict__ D_skip,
    const float* __restrict__ carry, float* __restrict__ y)
{
    const int tid = threadIdx.x;
    const int s  = tid & 15;
    const int dg = tid >> 4;
    int blk = blockIdx.x;
    const int dblk = blk % NDB; blk /= NDB;
    const int c = blk % NC;
    const int b = blk / NC;
    const int d = dblk * 16 + dg;

    const float Ads = -expf(A_log[(size_t)d * DS + s]);
    const float Dd  = D_skip[d];
    const float cv  = carry[(((size_t)b*NC + c)*DI + d)*DS + s];
    float S = 0.f;
    const int t0 = c * CL;
    const float* dtp = dt    + ((size_t)b*LL + t0)*DI + d;
    const float* hp  = hconv + ((size_t)b*LL + t0)*DI + d;
    const float* sp  = ssm   + ((size_t)b*LL + t0)*SSMW;
    const float* gp  = proj  + ((size_t)b*LL + t0)*(2*DI) + DI + d;
    float*       yp  = y     + ((size_t)b*LL + t0)*DI + d;

    for (int t = 0; t < CL; ++t) {
        float dtv = dtp[(size_t)t * DI];
        S += dtv;
        float Cv = sp[(size_t)t * SSMW + DTR + DS + s];
        float contrib = expf(Ads * S) * cv * Cv;
        contrib += __shfl_xor(contrib, 1, 16);
        contrib += __shfl_xor(contrib, 2, 16);
        contrib += __shfl_xor(contrib, 4, 16);
        contrib += __shfl_xor(contrib, 8, 16);
        if (s == 0) {
            float hv  = hp[(size_t)t * DI];
            float ylo = yp[(size_t)t * DI];
            float gv  = gp[(size_t)t * (2*DI)];
            float sig = 1.f / (1.f + expf(-gv));
            yp[(size_t)t * DI] = (ylo + contrib + Dd * hv) * (gv * sig);
        }
    }
}

// ---------------------------------------------------------------------------
// Launch
// ---------------------------------------------------------------------------
extern "C" void kernel_launch(void* const* d_in, const int* in_sizes, int n_in,
                              void* d_out, int out_size, void* d_ws, size_t ws_size,
                              hipStream_t stream)
{
    const int*   ids        = (const int*)  d_in[0];
    const float* embed      = (const float*)d_in[1];
    const float* norm_f_w   = (const float*)d_in[2];
    const float* in_proj_w  = (const float*)d_in[3];
    const float* conv_w     = (const float*)d_in[4];
    const float* conv_b     = (const float*)d_in[5];
    const float* x_proj_w   = (const float*)d_in[6];
    const float* dt_proj_w  = (const float*)d_in[7];
    const float* dt_proj_b  = (const float*)d_in[8];
    const float* A_log      = (const float*)d_in[9];
    const float* D_skip     = (const float*)d_in[10];
    const float* out_proj_w = (const float*)d_in[11];
    const float* norm_w     = (const float*)d_in[12];
    float* out = (float*)d_out;

    // fp32 workspace region
    float* ws    = (float*)d_ws;
    float* h     = ws;
    float* xn    = h     + ROWS * DM;
    float* proj  = xn    + ROWS * DM;
    float* hconv = proj  + ROWS * 2 * DI;
    float* ssm   = hconv + ROWS * DI;
    float* dtb   = ssm   + ROWS * SSMW;
    float* yb    = dtb   + ROWS * DI;
    float* Ebuf  = yb    + ROWS * DI;
    float* Pbuf  = Ebuf  + (size_t)BB*NC*DI*DS;
    float* cbuf  = Pbuf  + (size_t)BB*NC*DI*DS;
    float* xpart = cbuf  + (size_t)BB*NC*DI*DS;      // [XP_KS, ROWS, SSMW]
    const size_t F32_FLOATS = (size_t)ROWS * (DM + DM + 2*DI + DI + SSMW + DI + DI)
                            + 3 * (size_t)BB*NC*DI*DS
                            + (size_t)XP_KS*ROWS*SSMW;

    // bf16 split planes (embed LAST so tier-1 works with smaller ws)
    const size_t IPW_E = (size_t)NL * 2 * DI * DM;
    const size_t OPW_E = (size_t)NL * DM * DI;
    const size_t ACT_E = (size_t)ROWS * DI;
    const size_t EMB_E = (size_t)VOCAB_ * DM;
    unsigned short* u0   = (unsigned short*)(ws + F32_FLOATS);
    unsigned short* ipwh = u0;
    unsigned short* ipwl = ipwh + IPW_E;
    unsigned short* opwh = ipwl + IPW_E;
    unsigned short* opwl = opwh + OPW_E;
    unsigned short* acth = opwl + OPW_E;
    unsigned short* actl = acth + ACT_E;
    unsigned short* embh = actl + ACT_E;
    unsigned short* embl = embh + EMB_E;
    const size_t NEED_PROJ = F32_FLOATS*4 + 2*2*(IPW_E + OPW_E + ACT_E);
    const size_t NEED_HEAD = NEED_PROJ + 2*2*EMB_E;
    const bool mfma_proj = ws_size >= NEED_PROJ;
    const bool mfma_head = ws_size >= NEED_HEAD;

    gather_kernel<<<(ROWS * DM + 255) / 256, 256, 0, stream>>>(ids, embed, h, ROWS * DM);

    if (mfma_proj) {
        split_kernel<<<(int)(IPW_E/4 + 255)/256, 256, 0, stream>>>(in_proj_w,  ipwh, ipwl, (int)(IPW_E/4));
        split_kernel<<<(int)(OPW_E/4 + 255)/256, 256, 0, stream>>>(out_proj_w, opwh, opwl, (int)(OPW_E/4));
    }
    if (mfma_head) {
        split_kernel<<<(int)(EMB_E/4 + 255)/256, 256, 0, stream>>>(embed, embh, embl, (int)(EMB_E/4));
    }

    for (int i = 0; i < NL; ++i) {
        const float* ipw = in_proj_w  + (size_t)i * 2 * DI * DM;
        const float* cw  = conv_w     + (size_t)i * DI * DCONV;
        const float* cb  = conv_b     + (size_t)i * DI;
        const float* xpw = x_proj_w   + (size_t)i * SSMW * DI;
        const float* dpw = dt_proj_w  + (size_t)i * DI * DTR;
        const float* dpb = dt_proj_b  + (size_t)i * DI;
        const float* al  = A_log      + (size_t)i * DI * DS;
        const float* dsk = D_skip     + (size_t)i * DI;
        const float* opw = out_proj_w + (size_t)i * DM * DI;
        const float* nw  = norm_w     + (size_t)i * DM;

        rmsnorm_kernel<<<ROWS, 256, 0, stream>>>(h, nw, xn, DM);

        if (mfma_proj) {
            split_kernel<<<(ROWS*DM/4 + 255)/256, 256, 0, stream>>>(xn, acth, actl, ROWS*DM/4);
            gemm_mfma<0><<<dim3(ROWS/128, (2*DI)/128), 256, 0, stream>>>(
                acth, actl, DM, ipwh + (size_t)i*2*DI*DM, ipwl + (size_t)i*2*DI*DM, DM,
                proj, 2*DI, DM, nullptr);
        } else {
            gemm_tn<0><<<dim3(ROWS/64, (2*DI)/64), 256, 0, stream>>>(
                xn, DM, ipw, DM, proj, 2*DI, ROWS, 2*DI, DM, nullptr, nullptr);
        }

        conv_silu_kernel<<<(ROWS * DI + 255) / 256, 256, 0, stream>>>(proj, cw, cb, hconv);

        // x_proj: split-K skinny GEMM (512 blocks) + reduce
        xproj_partial_kernel<<<dim3(ROWS/32, XP_KS), 256, 0, stream>>>(hconv, xpw, xpart);
        xproj_reduce_kernel<<<(ROWS*SSMW + 255)/256, 256, 0, stream>>>(xpart, ssm);

        gemm_tn<1><<<dim3(ROWS / 64, DI / 64), 256, 0, stream>>>(
            ssm, SSMW, dpw, DTR, dtb, DI, ROWS, DI, DTR, dpb, nullptr);

        // chunked scan: local -> carry -> fix
        scan_local_kernel<<<BB*NC*NDB, 256, 0, stream>>>(dtb, hconv, ssm, al, yb, Ebuf, Pbuf);
        scan_carry_kernel<<<(BB*DI*DS + 255)/256, 256, 0, stream>>>(Ebuf, Pbuf, cbuf);
        scan_fix_kernel<<<BB*NC*NDB, 256, 0, stream>>>(dtb, hconv, ssm, proj, al, dsk, cbuf, yb);

        if (mfma_proj) {
            split_kernel<<<(ROWS*DI/4 + 255)/256, 256, 0, stream>>>(yb, acth, actl, ROWS*DI/4);
            gemm_mfma<2><<<dim3(ROWS/128, DM/128), 256, 0, stream>>>(
                acth, actl, DI, opwh + (size_t)i*DM*DI, opwl + (size_t)i*DM*DI, DI,
                h, DM, DI, h);
        } else {
            gemm_tn<2><<<dim3(ROWS/64, DM/64), 256, 0, stream>>>(
                yb, DI, opw, DI, h, DM, ROWS, DM, DI, nullptr, h);
        }
    }

    rmsnorm_kernel<<<ROWS, 256, 0, stream>>>(h, norm_f_w, xn, DM);
    if (mfma_head) {
        split_kernel<<<(ROWS*DM/4 + 255)/256, 256, 0, stream>>>(xn, acth, actl, ROWS*DM/4);
        gemm_mfma<0><<<dim3(ROWS/128, VOCAB_/128), 256, 0, stream>>>(
            acth, actl, DM, embh, embl, DM, out, VOCAB_, DM, nullptr);
    } else {
        gemm_tn<0><<<dim3(ROWS/64, VOCAB_/64), 256, 0, stream>>>(
            xn, DM, embed, DM, out, VOCAB_, ROWS, VOCAB_, DM, nullptr, nullptr);
    }
}

// Round 6
// 1238.361 us; speedup vs baseline: 4.7051x; 1.1576x over previous
//
#include <hip/hip_runtime.h>
#include <hip/hip_bf16.h>
#include <math.h>

// Model dims (compile-time constants)
#define NL 4
#define DM 768
#define DI 1536
#define DS 16
#define DTR 48
#define DCONV 4
#define VOCAB_ 32000
#define BB 2
#define LL 512
#define ROWS (BB*LL)   // 1024
#define SSMW (DTR + 2*DS)  // 80
#define NC 32              // scan chunks
#define CL (LL/NC)         // 16 steps per chunk
#define NDB (DI/16)        // 96 d-blocks
#define XP_KS 16           // x_proj split-K factor
#define XP_KC (DI/XP_KS)   // 96
#define OP_KS 4            // out_proj split-K factor
#define OP_KC (DI/OP_KS)   // 384

typedef __bf16 bf16x8 __attribute__((ext_vector_type(8)));
typedef float f32x4 __attribute__((ext_vector_type(4)));

// ---------------------------------------------------------------------------
// fp32 -> bf16 split helpers (RNE)
// ---------------------------------------------------------------------------
__device__ __forceinline__ unsigned short f2bf(float f) {
    unsigned u = __float_as_uint(f);
    u = u + 0x7fffu + ((u >> 16) & 1u);
    return (unsigned short)(u >> 16);
}
__device__ __forceinline__ float bf2f(unsigned short b) {
    return __uint_as_float((unsigned)b << 16);
}

__global__ __launch_bounds__(256) void split_kernel(
    const float* __restrict__ x,
    unsigned short* __restrict__ hi, unsigned short* __restrict__ lo, int n4)
{
    int i = blockIdx.x * 256 + threadIdx.x;
    if (i >= n4) return;
    const float4 v = ((const float4*)x)[i];
    float vv[4] = {v.x, v.y, v.z, v.w};
    unsigned short hh[4], ll[4];
    #pragma unroll
    for (int j = 0; j < 4; j++) {
        hh[j] = f2bf(vv[j]);
        ll[j] = f2bf(vv[j] - bf2f(hh[j]));
    }
    ((ushort4*)hi)[i] = make_ushort4(hh[0], hh[1], hh[2], hh[3]);
    ((ushort4*)lo)[i] = make_ushort4(ll[0], ll[1], ll[2], ll[3]);
}

// ---------------------------------------------------------------------------
// global -> LDS 16B async copy
// ---------------------------------------------------------------------------
__device__ __forceinline__ void gld16(void* l, const void* g) {
    __builtin_amdgcn_global_load_lds(
        (const __attribute__((address_space(1))) void*)g,
        (__attribute__((address_space(3))) void*)l, 16, 0, 0);
}

// ---------------------------------------------------------------------------
// bf16x3 MFMA GEMM (hi*hi + hi*lo + lo*hi), 128x128 tile, BK=32, 4 waves.
// 1D grid (x = gx*gy blocks, must be %8==0) with XCD panel-major swizzle:
//   bid -> v = (bid&7)*(nb/8) + (bid>>3); bx = v%gx (M-block), by = v/gx.
// All 8 M-blocks of an N-panel are v-adjacent -> co-resident on one XCD ->
// B panel fetched once per XCD L2 instead of 8x.
// blockIdx.y = split-K slice z: K is the chunk size, k-base = z*K,
// C += z*zstride (zstride=0 and gridDim.y=1 for non-split calls).
// EPI: 0 = none, 2 = +resid
// ---------------------------------------------------------------------------
template<int EPI>
__global__ __launch_bounds__(256) void gemm_mfma(
    const unsigned short* __restrict__ Ahi, const unsigned short* __restrict__ Alo, int lda,
    const unsigned short* __restrict__ Bhi, const unsigned short* __restrict__ Blo, int ldb,
    float* __restrict__ C, int ldc, int K,
    const float* __restrict__ resid, int gx, size_t zstride)
{
    __shared__ __align__(16) unsigned short sAh[128*32];
    __shared__ __align__(16) unsigned short sAl[128*32];
    __shared__ __align__(16) unsigned short sBh[128*32];
    __shared__ __align__(16) unsigned short sBl[128*32];

    const int tid  = threadIdx.x;
    const int lane = tid & 63;
    // XCD panel-major swizzle (nb % 8 == 0 for all call sites)
    const int nb = gridDim.x;
    const int v  = (blockIdx.x & 7) * (nb >> 3) + (blockIdx.x >> 3);
    const int m0 = (v % gx) * 128;
    const int n0 = (v / gx) * 128;
    const int kb = (int)blockIdx.y * K;
    C += (size_t)blockIdx.y * zstride;

    const int w  = tid >> 6;
    const int wr = (w >> 1) * 64;
    const int wc = (w & 1) * 64;

    f32x4 acc[4][4];
    #pragma unroll
    for (int i = 0; i < 4; i++)
        #pragma unroll
        for (int j = 0; j < 4; j++)
            acc[i][j] = (f32x4){0.f, 0.f, 0.f, 0.f};

    const int srow = tid >> 2;
    const int ps   = tid & 3;
    const int lsl  = ps ^ ((srow >> 1) & 3);

    int offA[4], offB[4];
    #pragma unroll
    for (int i = 0; i < 4; i++) {
        int ra = wr + i*16 + (lane & 15);
        int pa = (lane >> 4) ^ ((ra >> 1) & 3);
        offA[i] = ra*32 + pa*8;
        int rb = wc + i*16 + (lane & 15);
        int pb = (lane >> 4) ^ ((rb >> 1) & 3);
        offB[i] = rb*32 + pb*8;
    }

    for (int k0 = kb; k0 < kb + K; k0 += 32) {
        const size_t a1 = (size_t)(m0 + srow)      * lda + k0 + lsl*8;
        const size_t a2 = (size_t)(m0 + 64 + srow) * lda + k0 + lsl*8;
        const size_t b1 = (size_t)(n0 + srow)      * ldb + k0 + lsl*8;
        const size_t b2 = (size_t)(n0 + 64 + srow) * ldb + k0 + lsl*8;
        gld16(&sAh[(size_t)tid*8],       Ahi + a1);
        gld16(&sAh[(size_t)(256+tid)*8], Ahi + a2);
        gld16(&sAl[(size_t)tid*8],       Alo + a1);
        gld16(&sAl[(size_t)(256+tid)*8], Alo + a2);
        gld16(&sBh[(size_t)tid*8],       Bhi + b1);
        gld16(&sBh[(size_t)(256+tid)*8], Bhi + b2);
        gld16(&sBl[(size_t)tid*8],       Blo + b1);
        gld16(&sBl[(size_t)(256+tid)*8], Blo + b2);
        __syncthreads();

        bf16x8 ah[4], al[4], bh[4], bl[4];
        #pragma unroll
        for (int i = 0; i < 4; i++) {
            ah[i] = *(const bf16x8*)&sAh[offA[i]];
            al[i] = *(const bf16x8*)&sAl[offA[i]];
            bh[i] = *(const bf16x8*)&sBh[offB[i]];
            bl[i] = *(const bf16x8*)&sBl[offB[i]];
        }
        #pragma unroll
        for (int i = 0; i < 4; i++)
            #pragma unroll
            for (int j = 0; j < 4; j++) {
                acc[i][j] = __builtin_amdgcn_mfma_f32_16x16x32_bf16(ah[i], bh[j], acc[i][j], 0, 0, 0);
                acc[i][j] = __builtin_amdgcn_mfma_f32_16x16x32_bf16(ah[i], bl[j], acc[i][j], 0, 0, 0);
                acc[i][j] = __builtin_amdgcn_mfma_f32_16x16x32_bf16(al[i], bh[j], acc[i][j], 0, 0, 0);
            }
        __syncthreads();
    }

    #pragma unroll
    for (int i = 0; i < 4; i++) {
        int rbase = m0 + wr + i*16 + (lane >> 4)*4;
        #pragma unroll
        for (int j = 0; j < 4; j++) {
            int col = n0 + wc + j*16 + (lane & 15);
            #pragma unroll
            for (int r = 0; r < 4; r++) {
                float vv = acc[i][j][r];
                if (EPI == 2) vv += resid[(size_t)(rbase + r)*ldc + col];
                C[(size_t)(rbase + r)*ldc + col] = vv;
            }
        }
    }
}

// out_proj split-K reduce: h[i] += sum_z part[z][i]
__global__ __launch_bounds__(256) void opart_reduce_kernel(
    const float* __restrict__ part, float* __restrict__ h, int n)
{
    int i = blockIdx.x * 256 + threadIdx.x;
    if (i >= n) return;
    float s = h[i];
    #pragma unroll
    for (int z = 0; z < OP_KS; ++z)
        s += part[(size_t)z * n + i];
    h[i] = s;
}

// ---------------------------------------------------------------------------
// Embedding gather
// ---------------------------------------------------------------------------
__global__ __launch_bounds__(256) void gather_kernel(
    const int* __restrict__ ids, const float* __restrict__ embed,
    float* __restrict__ h, int n)
{
    int idx = blockIdx.x * 256 + threadIdx.x;
    if (idx >= n) return;
    int d = idx % DM;
    int tok = idx / DM;
    h[idx] = embed[(size_t)ids[tok] * DM + d];
}

// ---------------------------------------------------------------------------
// RMSNorm -> fp32 out (fallback path)
// ---------------------------------------------------------------------------
__global__ __launch_bounds__(256) void rmsnorm_kernel(
    const float* __restrict__ x, const float* __restrict__ w,
    float* __restrict__ out, int D)
{
    int row = blockIdx.x;
    const float* xr = x + (size_t)row * D;
    float ss = 0.f;
    for (int i = threadIdx.x; i < D; i += 256) { float v = xr[i]; ss += v * v; }
    for (int o = 32; o >= 1; o >>= 1) ss += __shfl_xor(ss, o, 64);
    __shared__ float sbuf[4];
    int wid = threadIdx.x >> 6;
    if ((threadIdx.x & 63) == 0) sbuf[wid] = ss;
    __syncthreads();
    if (threadIdx.x == 0) {
        float t = sbuf[0] + sbuf[1] + sbuf[2] + sbuf[3];
        sbuf[0] = 1.0f / sqrtf(t / (float)D + 1e-5f);
    }
    __syncthreads();
    float scale = sbuf[0];
    for (int i = threadIdx.x; i < D; i += 256)
        out[(size_t)row * D + i] = xr[i] * scale * w[i];
}

// ---------------------------------------------------------------------------
// RMSNorm -> bf16 hi/lo planes directly (MFMA path; kills split launches)
// ---------------------------------------------------------------------------
__global__ __launch_bounds__(256) void rmsnorm_split_kernel(
    const float* __restrict__ x, const float* __restrict__ w,
    unsigned short* __restrict__ hi, unsigned short* __restrict__ lo, int D)
{
    int row = blockIdx.x;
    const float* xr = x + (size_t)row * D;
    float ss = 0.f;
    for (int i = threadIdx.x; i < D; i += 256) { float v = xr[i]; ss += v * v; }
    for (int o = 32; o >= 1; o >>= 1) ss += __shfl_xor(ss, o, 64);
    __shared__ float sbuf[4];
    int wid = threadIdx.x >> 6;
    if ((threadIdx.x & 63) == 0) sbuf[wid] = ss;
    __syncthreads();
    if (threadIdx.x == 0) {
        float t = sbuf[0] + sbuf[1] + sbuf[2] + sbuf[3];
        sbuf[0] = 1.0f / sqrtf(t / (float)D + 1e-5f);
    }
    __syncthreads();
    float scale = sbuf[0];
    for (int i = threadIdx.x; i < D; i += 256) {
        float v = xr[i] * scale * w[i];
        unsigned short hh = f2bf(v);
        hi[(size_t)row * D + i] = hh;
        lo[(size_t)row * D + i] = f2bf(v - bf2f(hh));
    }
}

// ---------------------------------------------------------------------------
// fp32 GEMM (dt_proj and fallback)
// ---------------------------------------------------------------------------
template<int EPI>
__global__ __launch_bounds__(256) void gemm_tn(
    const float* __restrict__ A, int lda,
    const float* __restrict__ W, int ldw,
    float* __restrict__ C, int ldc,
    int M, int N, int K,
    const float* __restrict__ bias,
    const float* __restrict__ resid)
{
    const int tid = threadIdx.x;
    const int tx = tid & 15;
    const int ty = tid >> 4;
    const int m0 = blockIdx.x * 64;
    const int n0 = blockIdx.y * 64;

    __shared__ float As[16][65];
    __shared__ float Ws[16][65];

    float acc[4][4];
    #pragma unroll
    for (int i = 0; i < 4; i++)
        #pragma unroll
        for (int j = 0; j < 4; j++) acc[i][j] = 0.f;

    const int lrow = tid >> 2;
    const int lk   = (tid & 3) * 4;

    for (int k0 = 0; k0 < K; k0 += 16) {
        {
            int m = m0 + lrow;
            int n = n0 + lrow;
            #pragma unroll
            for (int j = 0; j < 4; j++) {
                int k = k0 + lk + j;
                As[lk + j][lrow] = (m < M && k < K) ? A[(size_t)m * lda + k] : 0.f;
                Ws[lk + j][lrow] = (n < N && k < K) ? W[(size_t)n * ldw + k] : 0.f;
            }
        }
        __syncthreads();
        #pragma unroll
        for (int k = 0; k < 16; k++) {
            float a[4], wv[4];
            #pragma unroll
            for (int i = 0; i < 4; i++) a[i] = As[k][ty * 4 + i];
            #pragma unroll
            for (int j = 0; j < 4; j++) wv[j] = Ws[k][tx * 4 + j];
            #pragma unroll
            for (int i = 0; i < 4; i++)
                #pragma unroll
                for (int j = 0; j < 4; j++)
                    acc[i][j] += a[i] * wv[j];
        }
        __syncthreads();
    }

    #pragma unroll
    for (int i = 0; i < 4; i++) {
        int m = m0 + ty * 4 + i;
        if (m >= M) continue;
        #pragma unroll
        for (int j = 0; j < 4; j++) {
            int n = n0 + tx * 4 + j;
            if (n >= N) continue;
            float v = acc[i][j];
            if (EPI == 1) {
                v += bias[n];
                v = fmaxf(v, 0.f) + log1pf(expf(-fabsf(v)));
            }
            if (EPI == 2) v += resid[(size_t)m * ldc + n];
            C[(size_t)m * ldc + n] = v;
        }
    }
}

// ---------------------------------------------------------------------------
// x_proj split-K skinny GEMM
// ---------------------------------------------------------------------------
__global__ __launch_bounds__(256) void xproj_partial_kernel(
    const float* __restrict__ A,    // hconv [ROWS, DI]
    const float* __restrict__ W,    // x_proj_w [SSMW, DI]
    float* __restrict__ part)       // [XP_KS, ROWS, SSMW]
{
    __shared__ float sA[32*97];
    __shared__ float sW[80*97];
    const int m0 = blockIdx.x * 32;
    const int k0 = blockIdx.y * XP_KC;

    for (int idx = threadIdx.x; idx < 32*XP_KC; idx += 256) {
        int r = idx / XP_KC, k = idx % XP_KC;
        sA[r*97 + k] = A[(size_t)(m0 + r)*DI + k0 + k];
    }
    for (int idx = threadIdx.x; idx < 80*XP_KC; idx += 256) {
        int r = idx / XP_KC, k = idx % XP_KC;
        sW[r*97 + k] = W[(size_t)r*DI + k0 + k];
    }
    __syncthreads();

    const int tr = (threadIdx.x >> 4) * 2;
    const int tc = (threadIdx.x & 15) * 5;
    float acc[2][5];
    #pragma unroll
    for (int i = 0; i < 2; i++)
        #pragma unroll
        for (int j = 0; j < 5; j++) acc[i][j] = 0.f;

    #pragma unroll 4
    for (int k = 0; k < XP_KC; ++k) {
        float a0 = sA[tr*97 + k];
        float a1 = sA[(tr+1)*97 + k];
        float w0 = sW[(tc+0)*97 + k];
        float w1 = sW[(tc+1)*97 + k];
        float w2 = sW[(tc+2)*97 + k];
        float w3 = sW[(tc+3)*97 + k];
        float w4 = sW[(tc+4)*97 + k];
        acc[0][0] += a0*w0; acc[0][1] += a0*w1; acc[0][2] += a0*w2;
        acc[0][3] += a0*w3; acc[0][4] += a0*w4;
        acc[1][0] += a1*w0; acc[1][1] += a1*w1; acc[1][2] += a1*w2;
        acc[1][3] += a1*w3; acc[1][4] += a1*w4;
    }

    float* pp = part + ((size_t)blockIdx.y * ROWS + m0) * SSMW;
    #pragma unroll
    for (int i = 0; i < 2; i++)
        #pragma unroll
        for (int j = 0; j < 5; j++)
            pp[(size_t)(tr + i)*SSMW + tc + j] = acc[i][j];
}

__global__ __launch_bounds__(256) void xproj_reduce_kernel(
    const float* __restrict__ part, float* __restrict__ ssmout)
{
    int i = blockIdx.x * 256 + threadIdx.x;
    if (i >= ROWS * SSMW) return;
    float s = 0.f;
    #pragma unroll
    for (int ks = 0; ks < XP_KS; ++ks)
        s += part[(size_t)ks * ROWS * SSMW + i];
    ssmout[i] = s;
}

// ---------------------------------------------------------------------------
// Causal depthwise conv (k=4) + SiLU
// ---------------------------------------------------------------------------
__global__ __launch_bounds__(256) void conv_silu_kernel(
    const float* __restrict__ proj,
    const float* __restrict__ cw, const float* __restrict__ cb,
    float* __restrict__ hconv)
{
    int idx = blockIdx.x * 256 + threadIdx.x;
    if (idx >= ROWS * DI) return;
    int d = idx % DI;
    int bt = idx / DI;
    int t = bt % LL;
    float sum = cb[d];
    #pragma unroll
    for (int j = 0; j < DCONV; j++) {
        int tt = t - (DCONV - 1) + j;
        if (tt >= 0)
            sum += cw[d * DCONV + j] * proj[(size_t)(bt - (DCONV - 1) + j) * (2 * DI) + d];
    }
    float sig = 1.f / (1.f + expf(-sum));
    hconv[idx] = sum * sig;
}

// ---------------------------------------------------------------------------
// Chunked selective scan — pass 1: per-chunk local scan
// ---------------------------------------------------------------------------
__global__ __launch_bounds__(256) void scan_local_kernel(
    const float* __restrict__ dt, const float* __restrict__ hconv,
    const float* __restrict__ ssm, const float* __restrict__ A_log,
    float* __restrict__ ylocal, float* __restrict__ E, float* __restrict__ P)
{
    const int tid = threadIdx.x;
    const int s  = tid & 15;
    const int dg = tid >> 4;
    int blk = blockIdx.x;
    const int dblk = blk % NDB; blk /= NDB;
    const int c = blk % NC;
    const int b = blk / NC;
    const int d = dblk * 16 + dg;

    const float Ads = -expf(A_log[(size_t)d * DS + s]);
    float state = 0.f, Ssum = 0.f;
    const int t0 = c * CL;
    const float* dtp = dt     + ((size_t)b*LL + t0)*DI + d;
    const float* hp  = hconv  + ((size_t)b*LL + t0)*DI + d;
    const float* sp  = ssm    + ((size_t)b*LL + t0)*SSMW;
    float*       yp  = ylocal + ((size_t)b*LL + t0)*DI + d;

    for (int t = 0; t < CL; ++t) {
        float dtv = dtp[(size_t)t * DI];
        float hv  = hp[(size_t)t * DI];
        float Bv  = sp[(size_t)t * SSMW + DTR + s];
        float Cv  = sp[(size_t)t * SSMW + DTR + DS + s];
        float dA  = expf(dtv * Ads);
        state = dA * state + dtv * hv * Bv;
        Ssum += dtv;
        float contrib = state * Cv;
        contrib += __shfl_xor(contrib, 1, 16);
        contrib += __shfl_xor(contrib, 2, 16);
        contrib += __shfl_xor(contrib, 4, 16);
        contrib += __shfl_xor(contrib, 8, 16);
        if (s == 0) yp[(size_t)t * DI] = contrib;
    }
    const size_t si = (((size_t)b*NC + c)*DI + d)*DS + s;
    E[si] = state;
    P[si] = expf(Ads * Ssum);
}

// ---------------------------------------------------------------------------
// Pass 2: carry combine
// ---------------------------------------------------------------------------
__global__ __launch_bounds__(256) void scan_carry_kernel(
    const float* __restrict__ E, const float* __restrict__ P,
    float* __restrict__ carry)
{
    int g = blockIdx.x * 256 + threadIdx.x;
    if (g >= BB * DI * DS) return;
    int b   = g / (DI * DS);
    int dsi = g % (DI * DS);
    float cv = 0.f;
    for (int c = 0; c < NC; ++c) {
        size_t idx = ((size_t)b*NC + c)*(DI*DS) + dsi;
        carry[idx] = cv;
        cv = P[idx] * cv + E[idx];
    }
}

// ---------------------------------------------------------------------------
// Pass 3: fix-up + epilogue. PLANES=1 -> write bf16 hi/lo planes for out_proj
// ---------------------------------------------------------------------------
template<int PLANES>
__global__ __launch_bounds__(256) void scan_fix_kernel(
    const float* __restrict__ dt, const float* __restrict__ hconv,
    const float* __restrict__ ssm, const float* __restrict__ proj,
    const float* __restrict__ A_log, const float* __restrict__ D_skip,
    const float* __restrict__ carry, float* __restrict__ y,
    unsigned short* __restrict__ yhi, unsigned short* __restrict__ ylo)
{
    const int tid = threadIdx.x;
    const int s  = tid & 15;
    const int dg = tid >> 4;
    int blk = blockIdx.x;
    const int dblk = blk % NDB; blk /= NDB;
    const int c = blk % NC;
    const int b = blk / NC;
    const int d = dblk * 16 + dg;

    const float Ads = -expf(A_log[(size_t)d * DS + s]);
    const float Dd  = D_skip[d];
    const float cv  = carry[(((size_t)b*NC + c)*DI + d)*DS + s];
    float S = 0.f;
    const int t0 = c * CL;
    const float* dtp = dt    + ((size_t)b*LL + t0)*DI + d;
    const float* hp  = hconv + ((size_t)b*LL + t0)*DI + d;
    const float* sp  = ssm   + ((size_t)b*LL + t0)*SSMW;
    const float* gp  = proj  + ((size_t)b*LL + t0)*(2*DI) + DI + d;
    const size_t yoff = ((size_t)b*LL + t0)*DI + d;

    for (int t = 0; t < CL; ++t) {
        float dtv = dtp[(size_t)t * DI];
        S += dtv;
        float Cv = sp[(size_t)t * SSMW + DTR + DS + s];
        float contrib = expf(Ads * S) * cv * Cv;
        contrib += __shfl_xor(contrib, 1, 16);
        contrib += __shfl_xor(contrib, 2, 16);
        contrib += __shfl_xor(contrib, 4, 16);
        contrib += __shfl_xor(contrib, 8, 16);
        if (s == 0) {
            float hv  = hp[(size_t)t * DI];
            float ylv = y[yoff + (size_t)t * DI];
            float gv  = gp[(size_t)t * (2*DI)];
            float sig = 1.f / (1.f + expf(-gv));
            float yv  = (ylv + contrib + Dd * hv) * (gv * sig);
            if (PLANES) {
                unsigned short hh = f2bf(yv);
                yhi[yoff + (size_t)t * DI] = hh;
                ylo[yoff + (size_t)t * DI] = f2bf(yv - bf2f(hh));
            } else {
                y[yoff + (size_t)t * DI] = yv;
            }
        }
    }
}

// ---------------------------------------------------------------------------
// Launch
// ---------------------------------------------------------------------------
extern "C" void kernel_launch(void* const* d_in, const int* in_sizes, int n_in,
                              void* d_out, int out_size, void* d_ws, size_t ws_size,
                              hipStream_t stream)
{
    const int*   ids        = (const int*)  d_in[0];
    const float* embed      = (const float*)d_in[1];
    const float* norm_f_w   = (const float*)d_in[2];
    const float* in_proj_w  = (const float*)d_in[3];
    const float* conv_w     = (const float*)d_in[4];
    const float* conv_b     = (const float*)d_in[5];
    const float* x_proj_w   = (const float*)d_in[6];
    const float* dt_proj_w  = (const float*)d_in[7];
    const float* dt_proj_b  = (const float*)d_in[8];
    const float* A_log      = (const float*)d_in[9];
    const float* D_skip     = (const float*)d_in[10];
    const float* out_proj_w = (const float*)d_in[11];
    const float* norm_w     = (const float*)d_in[12];
    float* out = (float*)d_out;

    // fp32 workspace region
    float* ws    = (float*)d_ws;
    float* h     = ws;
    float* xn    = h     + ROWS * DM;               // fallback only
    float* proj  = xn    + ROWS * DM;
    float* hconv = proj  + ROWS * 2 * DI;
    float* ssm   = hconv + ROWS * DI;
    float* dtb   = ssm   + ROWS * SSMW;
    float* yb    = dtb   + ROWS * DI;
    float* Ebuf  = yb    + ROWS * DI;
    float* Pbuf  = Ebuf  + (size_t)BB*NC*DI*DS;
    float* cbuf  = Pbuf  + (size_t)BB*NC*DI*DS;
    float* xpart = cbuf  + (size_t)BB*NC*DI*DS;      // [XP_KS, ROWS, SSMW]
    float* opart = xpart + (size_t)XP_KS*ROWS*SSMW;  // [OP_KS, ROWS, DM]
    const size_t F32_FLOATS = (size_t)ROWS * (DM + DM + 2*DI + DI + SSMW + DI + DI)
                            + 3 * (size_t)BB*NC*DI*DS
                            + (size_t)XP_KS*ROWS*SSMW
                            + (size_t)OP_KS*ROWS*DM;

    // bf16 split planes (embed LAST so tier-1 works with smaller ws)
    const size_t IPW_E = (size_t)NL * 2 * DI * DM;
    const size_t OPW_E = (size_t)NL * DM * DI;
    const size_t ACT_E = (size_t)ROWS * DI;
    const size_t EMB_E = (size_t)VOCAB_ * DM;
    unsigned short* u0   = (unsigned short*)(ws + F32_FLOATS);
    unsigned short* ipwh = u0;
    unsigned short* ipwl = ipwh + IPW_E;
    unsigned short* opwh = ipwl + IPW_E;
    unsigned short* opwl = opwh + OPW_E;
    unsigned short* acth = opwl + OPW_E;
    unsigned short* actl = acth + ACT_E;
    unsigned short* embh = actl + ACT_E;
    unsigned short* embl = embh + EMB_E;
    const size_t NEED_PROJ = F32_FLOATS*4 + 2*2*(IPW_E + OPW_E + ACT_E);
    const size_t NEED_HEAD = NEED_PROJ + 2*2*EMB_E;
    const bool mfma_proj = ws_size >= NEED_PROJ;
    const bool mfma_head = ws_size >= NEED_HEAD;

    gather_kernel<<<(ROWS * DM + 255) / 256, 256, 0, stream>>>(ids, embed, h, ROWS * DM);

    if (mfma_proj) {
        split_kernel<<<(int)(IPW_E/4 + 255)/256, 256, 0, stream>>>(in_proj_w,  ipwh, ipwl, (int)(IPW_E/4));
        split_kernel<<<(int)(OPW_E/4 + 255)/256, 256, 0, stream>>>(out_proj_w, opwh, opwl, (int)(OPW_E/4));
    }
    if (mfma_head) {
        split_kernel<<<(int)(EMB_E/4 + 255)/256, 256, 0, stream>>>(embed, embh, embl, (int)(EMB_E/4));
    }

    for (int i = 0; i < NL; ++i) {
        const float* ipw = in_proj_w  + (size_t)i * 2 * DI * DM;
        const float* cw  = conv_w     + (size_t)i * DI * DCONV;
        const float* cb  = conv_b     + (size_t)i * DI;
        const float* xpw = x_proj_w   + (size_t)i * SSMW * DI;
        const float* dpw = dt_proj_w  + (size_t)i * DI * DTR;
        const float* dpb = dt_proj_b  + (size_t)i * DI;
        const float* al  = A_log      + (size_t)i * DI * DS;
        const float* dsk = D_skip     + (size_t)i * DI;
        const float* opw = out_proj_w + (size_t)i * DM * DI;
        const float* nw  = norm_w     + (size_t)i * DM;

        if (mfma_proj) {
            // fused rmsnorm -> bf16 planes
            rmsnorm_split_kernel<<<ROWS, 256, 0, stream>>>(h, nw, acth, actl, DM);
            gemm_mfma<0><<<dim3(8*24, 1), 256, 0, stream>>>(
                acth, actl, DM, ipwh + (size_t)i*2*DI*DM, ipwl + (size_t)i*2*DI*DM, DM,
                proj, 2*DI, DM, nullptr, 8, 0);
        } else {
            rmsnorm_kernel<<<ROWS, 256, 0, stream>>>(h, nw, xn, DM);
            gemm_tn<0><<<dim3(ROWS/64, (2*DI)/64), 256, 0, stream>>>(
                xn, DM, ipw, DM, proj, 2*DI, ROWS, 2*DI, DM, nullptr, nullptr);
        }

        conv_silu_kernel<<<(ROWS * DI + 255) / 256, 256, 0, stream>>>(proj, cw, cb, hconv);

        // x_proj: split-K skinny GEMM + reduce
        xproj_partial_kernel<<<dim3(ROWS/32, XP_KS), 256, 0, stream>>>(hconv, xpw, xpart);
        xproj_reduce_kernel<<<(ROWS*SSMW + 255)/256, 256, 0, stream>>>(xpart, ssm);

        gemm_tn<1><<<dim3(ROWS / 64, DI / 64), 256, 0, stream>>>(
            ssm, SSMW, dpw, DTR, dtb, DI, ROWS, DI, DTR, dpb, nullptr);

        // chunked scan: local -> carry -> fix
        scan_local_kernel<<<BB*NC*NDB, 256, 0, stream>>>(dtb, hconv, ssm, al, yb, Ebuf, Pbuf);
        scan_carry_kernel<<<(BB*DI*DS + 255)/256, 256, 0, stream>>>(Ebuf, Pbuf, cbuf);

        if (mfma_proj) {
            // fix-up writes bf16 planes directly for out_proj
            scan_fix_kernel<1><<<BB*NC*NDB, 256, 0, stream>>>(
                dtb, hconv, ssm, proj, al, dsk, cbuf, yb, acth, actl);
            // out_proj split-K (4 x 48 blocks) then residual reduce
            gemm_mfma<0><<<dim3(8*6, OP_KS), 256, 0, stream>>>(
                acth, actl, DI, opwh + (size_t)i*DM*DI, opwl + (size_t)i*DM*DI, DI,
                opart, DM, OP_KC, nullptr, 8, (size_t)ROWS*DM);
            opart_reduce_kernel<<<(ROWS*DM + 255)/256, 256, 0, stream>>>(opart, h, ROWS*DM);
        } else {
            scan_fix_kernel<0><<<BB*NC*NDB, 256, 0, stream>>>(
                dtb, hconv, ssm, proj, al, dsk, cbuf, yb, nullptr, nullptr);
            gemm_tn<2><<<dim3(ROWS/64, DM/64), 256, 0, stream>>>(
                yb, DI, opw, DI, h, DM, ROWS, DM, DI, nullptr, h);
        }
    }

    if (mfma_head) {
        rmsnorm_split_kernel<<<ROWS, 256, 0, stream>>>(h, norm_f_w, acth, actl, DM);
        gemm_mfma<0><<<dim3(8*250, 1), 256, 0, stream>>>(
            acth, actl, DM, embh, embl, DM, out, VOCAB_, DM, nullptr, 8, 0);
    } else {
        rmsnorm_kernel<<<ROWS, 256, 0, stream>>>(h, norm_f_w, xn, DM);
        gemm_tn<0><<<dim3(ROWS/64, VOCAB_/64), 256, 0, stream>>>(
            xn, DM, embed, DM, out, VOCAB_, ROWS, VOCAB_, DM, nullptr, nullptr);
    }
}

// Round 8
// 1225.662 us; speedup vs baseline: 4.7538x; 1.0104x over previous
//
#include <hip/hip_runtime.h>
#include <hip/hip_bf16.h>
#include <math.h>

// Model dims (compile-time constants)
#define NL 4
#define DM 768
#define DI 1536
#define DS 16
#define DTR 48
#define DCONV 4
#define VOCAB_ 32000
#define BB 2
#define LL 512
#define ROWS (BB*LL)   // 1024
#define SSMW (DTR + 2*DS)  // 80
#define NC 32              // scan chunks
#define CL (LL/NC)         // 16 steps per chunk
#define NDB (DI/16)        // 96 d-blocks
#define XP_KS 16           // x_proj split-K factor
#define XP_KC (DI/XP_KS)   // 96
#define OP_KS 4            // out_proj split-K factor
#define OP_KC (DI/OP_KS)   // 384
#define DTB 96             // dt_proj N-block

typedef __bf16 bf16x8 __attribute__((ext_vector_type(8)));
typedef float f32x4 __attribute__((ext_vector_type(4)));

// ---------------------------------------------------------------------------
// fp32 -> bf16 split helpers (RNE)
// ---------------------------------------------------------------------------
__device__ __forceinline__ unsigned short f2bf(float f) {
    unsigned u = __float_as_uint(f);
    u = u + 0x7fffu + ((u >> 16) & 1u);
    return (unsigned short)(u >> 16);
}
__device__ __forceinline__ float bf2f(unsigned short b) {
    return __uint_as_float((unsigned)b << 16);
}

__global__ __launch_bounds__(256) void split_kernel(
    const float* __restrict__ x,
    unsigned short* __restrict__ hi, unsigned short* __restrict__ lo, int n4)
{
    int i = blockIdx.x * 256 + threadIdx.x;
    if (i >= n4) return;
    const float4 v = ((const float4*)x)[i];
    float vv[4] = {v.x, v.y, v.z, v.w};
    unsigned short hh[4], ll[4];
    #pragma unroll
    for (int j = 0; j < 4; j++) {
        hh[j] = f2bf(vv[j]);
        ll[j] = f2bf(vv[j] - bf2f(hh[j]));
    }
    ((ushort4*)hi)[i] = make_ushort4(hh[0], hh[1], hh[2], hh[3]);
    ((ushort4*)lo)[i] = make_ushort4(ll[0], ll[1], ll[2], ll[3]);
}

// ---------------------------------------------------------------------------
// global -> LDS 16B async copy
// ---------------------------------------------------------------------------
__device__ __forceinline__ void gld16(void* l, const void* g) {
    __builtin_amdgcn_global_load_lds(
        (const __attribute__((address_space(1))) void*)g,
        (__attribute__((address_space(3))) void*)l, 16, 0, 0);
}

// ---------------------------------------------------------------------------
// bf16x3 MFMA GEMM (hi*hi + hi*lo + lo*hi), 128x128 tile, BK=32, 4 waves.
// 1D grid (x = gx*gy blocks, %8==0) with XCD panel-major swizzle.
// blockIdx.y = split-K slice: k-base = z*K, C += z*zstride.
// ---------------------------------------------------------------------------
template<int EPI>
__global__ __launch_bounds__(256) void gemm_mfma(
    const unsigned short* __restrict__ Ahi, const unsigned short* __restrict__ Alo, int lda,
    const unsigned short* __restrict__ Bhi, const unsigned short* __restrict__ Blo, int ldb,
    float* __restrict__ C, int ldc, int K,
    const float* __restrict__ resid, int gx, size_t zstride)
{
    __shared__ __align__(16) unsigned short sAh[128*32];
    __shared__ __align__(16) unsigned short sAl[128*32];
    __shared__ __align__(16) unsigned short sBh[128*32];
    __shared__ __align__(16) unsigned short sBl[128*32];

    const int tid  = threadIdx.x;
    const int lane = tid & 63;
    const int nb = gridDim.x;
    const int v  = (blockIdx.x & 7) * (nb >> 3) + (blockIdx.x >> 3);
    const int m0 = (v % gx) * 128;
    const int n0 = (v / gx) * 128;
    const int kb = (int)blockIdx.y * K;
    C += (size_t)blockIdx.y * zstride;

    const int w  = tid >> 6;
    const int wr = (w >> 1) * 64;
    const int wc = (w & 1) * 64;

    f32x4 acc[4][4];
    #pragma unroll
    for (int i = 0; i < 4; i++)
        #pragma unroll
        for (int j = 0; j < 4; j++)
            acc[i][j] = (f32x4){0.f, 0.f, 0.f, 0.f};

    const int srow = tid >> 2;
    const int ps   = tid & 3;
    const int lsl  = ps ^ ((srow >> 1) & 3);

    int offA[4], offB[4];
    #pragma unroll
    for (int i = 0; i < 4; i++) {
        int ra = wr + i*16 + (lane & 15);
        int pa = (lane >> 4) ^ ((ra >> 1) & 3);
        offA[i] = ra*32 + pa*8;
        int rb = wc + i*16 + (lane & 15);
        int pb = (lane >> 4) ^ ((rb >> 1) & 3);
        offB[i] = rb*32 + pb*8;
    }

    for (int k0 = kb; k0 < kb + K; k0 += 32) {
        const size_t a1 = (size_t)(m0 + srow)      * lda + k0 + lsl*8;
        const size_t a2 = (size_t)(m0 + 64 + srow) * lda + k0 + lsl*8;
        const size_t b1 = (size_t)(n0 + srow)      * ldb + k0 + lsl*8;
        const size_t b2 = (size_t)(n0 + 64 + srow) * ldb + k0 + lsl*8;
        gld16(&sAh[(size_t)tid*8],       Ahi + a1);
        gld16(&sAh[(size_t)(256+tid)*8], Ahi + a2);
        gld16(&sAl[(size_t)tid*8],       Alo + a1);
        gld16(&sAl[(size_t)(256+tid)*8], Alo + a2);
        gld16(&sBh[(size_t)tid*8],       Bhi + b1);
        gld16(&sBh[(size_t)(256+tid)*8], Bhi + b2);
        gld16(&sBl[(size_t)tid*8],       Blo + b1);
        gld16(&sBl[(size_t)(256+tid)*8], Blo + b2);
        __syncthreads();

        bf16x8 ah[4], al[4], bh[4], bl[4];
        #pragma unroll
        for (int i = 0; i < 4; i++) {
            ah[i] = *(const bf16x8*)&sAh[offA[i]];
            al[i] = *(const bf16x8*)&sAl[offA[i]];
            bh[i] = *(const bf16x8*)&sBh[offB[i]];
            bl[i] = *(const bf16x8*)&sBl[offB[i]];
        }
        #pragma unroll
        for (int i = 0; i < 4; i++)
            #pragma unroll
            for (int j = 0; j < 4; j++) {
                acc[i][j] = __builtin_amdgcn_mfma_f32_16x16x32_bf16(ah[i], bh[j], acc[i][j], 0, 0, 0);
                acc[i][j] = __builtin_amdgcn_mfma_f32_16x16x32_bf16(ah[i], bl[j], acc[i][j], 0, 0, 0);
                acc[i][j] = __builtin_amdgcn_mfma_f32_16x16x32_bf16(al[i], bh[j], acc[i][j], 0, 0, 0);
            }
        __syncthreads();
    }

    #pragma unroll
    for (int i = 0; i < 4; i++) {
        int rbase = m0 + wr + i*16 + (lane >> 4)*4;
        #pragma unroll
        for (int j = 0; j < 4; j++) {
            int col = n0 + wc + j*16 + (lane & 15);
            #pragma unroll
            for (int r = 0; r < 4; r++) {
                float vv = acc[i][j][r];
                if (EPI == 2) vv += resid[(size_t)(rbase + r)*ldc + col];
                C[(size_t)(rbase + r)*ldc + col] = vv;
            }
        }
    }
}

// ---------------------------------------------------------------------------
// Embedding gather (fallback path)
// ---------------------------------------------------------------------------
__global__ __launch_bounds__(256) void gather_kernel(
    const int* __restrict__ ids, const float* __restrict__ embed,
    float* __restrict__ h, int n)
{
    int idx = blockIdx.x * 256 + threadIdx.x;
    if (idx >= n) return;
    int d = idx % DM;
    int tok = idx / DM;
    h[idx] = embed[(size_t)ids[tok] * DM + d];
}

// ---------------------------------------------------------------------------
// Fused: embed gather + rmsnorm + bf16 planes (layer-0 input). 1 block/row.
// ---------------------------------------------------------------------------
__global__ __launch_bounds__(256) void gather_norm_kernel(
    const int* __restrict__ ids, const float* __restrict__ embed,
    const float* __restrict__ w, float* __restrict__ h,
    unsigned short* __restrict__ hi, unsigned short* __restrict__ lo)
{
    __shared__ float buf[DM];
    __shared__ float sbuf[4];
    const int row = blockIdx.x;
    const int tok = ids[row];
    float ss = 0.f;
    for (int i = threadIdx.x; i < DM; i += 256) {
        float v = embed[(size_t)tok*DM + i];
        h[(size_t)row*DM + i] = v;
        buf[i] = v;
        ss += v*v;
    }
    for (int o = 32; o >= 1; o >>= 1) ss += __shfl_xor(ss, o, 64);
    int wid = threadIdx.x >> 6;
    if ((threadIdx.x & 63) == 0) sbuf[wid] = ss;
    __syncthreads();
    if (threadIdx.x == 0) {
        float t = sbuf[0]+sbuf[1]+sbuf[2]+sbuf[3];
        sbuf[0] = 1.0f / sqrtf(t/(float)DM + 1e-5f);
    }
    __syncthreads();
    float scale = sbuf[0];
    for (int i = threadIdx.x; i < DM; i += 256) {
        float v = buf[i]*scale*w[i];
        unsigned short hh = f2bf(v);
        hi[(size_t)row*DM+i] = hh;
        lo[(size_t)row*DM+i] = f2bf(v - bf2f(hh));
    }
}

// ---------------------------------------------------------------------------
// Fused: out_proj split-K reduce + residual + NEXT rmsnorm + planes. 1 blk/row.
// ---------------------------------------------------------------------------
__global__ __launch_bounds__(256) void opreduce_norm_kernel(
    const float* __restrict__ part,  // [OP_KS, ROWS, DM]
    const float* __restrict__ w,     // norm weight for next norm
    float* __restrict__ h,           // residual in/out
    unsigned short* __restrict__ hi, unsigned short* __restrict__ lo)
{
    __shared__ float buf[DM];
    __shared__ float sbuf[4];
    const int row = blockIdx.x;
    float ss = 0.f;
    for (int i = threadIdx.x; i < DM; i += 256) {
        float v = h[(size_t)row*DM + i];
        #pragma unroll
        for (int z = 0; z < OP_KS; ++z)
            v += part[(size_t)z*ROWS*DM + (size_t)row*DM + i];
        h[(size_t)row*DM + i] = v;
        buf[i] = v;
        ss += v*v;
    }
    for (int o = 32; o >= 1; o >>= 1) ss += __shfl_xor(ss, o, 64);
    int wid = threadIdx.x >> 6;
    if ((threadIdx.x & 63) == 0) sbuf[wid] = ss;
    __syncthreads();
    if (threadIdx.x == 0) {
        float t = sbuf[0]+sbuf[1]+sbuf[2]+sbuf[3];
        sbuf[0] = 1.0f / sqrtf(t/(float)DM + 1e-5f);
    }
    __syncthreads();
    float scale = sbuf[0];
    for (int i = threadIdx.x; i < DM; i += 256) {
        float v = buf[i]*scale*w[i];
        unsigned short hh = f2bf(v);
        hi[(size_t)row*DM+i] = hh;
        lo[(size_t)row*DM+i] = f2bf(v - bf2f(hh));
    }
}

// ---------------------------------------------------------------------------
// RMSNorm -> fp32 (fallback path)
// ---------------------------------------------------------------------------
__global__ __launch_bounds__(256) void rmsnorm_kernel(
    const float* __restrict__ x, const float* __restrict__ w,
    float* __restrict__ out, int D)
{
    int row = blockIdx.x;
    const float* xr = x + (size_t)row * D;
    float ss = 0.f;
    for (int i = threadIdx.x; i < D; i += 256) { float v = xr[i]; ss += v * v; }
    for (int o = 32; o >= 1; o >>= 1) ss += __shfl_xor(ss, o, 64);
    __shared__ float sbuf[4];
    int wid = threadIdx.x >> 6;
    if ((threadIdx.x & 63) == 0) sbuf[wid] = ss;
    __syncthreads();
    if (threadIdx.x == 0) {
        float t = sbuf[0] + sbuf[1] + sbuf[2] + sbuf[3];
        sbuf[0] = 1.0f / sqrtf(t / (float)D + 1e-5f);
    }
    __syncthreads();
    float scale = sbuf[0];
    for (int i = threadIdx.x; i < D; i += 256)
        out[(size_t)row * D + i] = xr[i] * scale * w[i];
}

// ---------------------------------------------------------------------------
// fp32 GEMM (fallback path only)
// ---------------------------------------------------------------------------
template<int EPI>
__global__ __launch_bounds__(256) void gemm_tn(
    const float* __restrict__ A, int lda,
    const float* __restrict__ W, int ldw,
    float* __restrict__ C, int ldc,
    int M, int N, int K,
    const float* __restrict__ bias,
    const float* __restrict__ resid)
{
    const int tid = threadIdx.x;
    const int tx = tid & 15;
    const int ty = tid >> 4;
    const int m0 = blockIdx.x * 64;
    const int n0 = blockIdx.y * 64;

    __shared__ float As[16][65];
    __shared__ float Ws[16][65];

    float acc[4][4];
    #pragma unroll
    for (int i = 0; i < 4; i++)
        #pragma unroll
        for (int j = 0; j < 4; j++) acc[i][j] = 0.f;

    const int lrow = tid >> 2;
    const int lk   = (tid & 3) * 4;

    for (int k0 = 0; k0 < K; k0 += 16) {
        {
            int m = m0 + lrow;
            int n = n0 + lrow;
            #pragma unroll
            for (int j = 0; j < 4; j++) {
                int k = k0 + lk + j;
                As[lk + j][lrow] = (m < M && k < K) ? A[(size_t)m * lda + k] : 0.f;
                Ws[lk + j][lrow] = (n < N && k < K) ? W[(size_t)n * ldw + k] : 0.f;
            }
        }
        __syncthreads();
        #pragma unroll
        for (int k = 0; k < 16; k++) {
            float a[4], wv[4];
            #pragma unroll
            for (int i = 0; i < 4; i++) a[i] = As[k][ty * 4 + i];
            #pragma unroll
            for (int j = 0; j < 4; j++) wv[j] = Ws[k][tx * 4 + j];
            #pragma unroll
            for (int i = 0; i < 4; i++)
                #pragma unroll
                for (int j = 0; j < 4; j++)
                    acc[i][j] += a[i] * wv[j];
        }
        __syncthreads();
    }

    #pragma unroll
    for (int i = 0; i < 4; i++) {
        int m = m0 + ty * 4 + i;
        if (m >= M) continue;
        #pragma unroll
        for (int j = 0; j < 4; j++) {
            int n = n0 + tx * 4 + j;
            if (n >= N) continue;
            float v = acc[i][j];
            if (EPI == 1) {
                v += bias[n];
                v = fmaxf(v, 0.f) + log1pf(expf(-fabsf(v)));
            }
            if (EPI == 2) v += resid[(size_t)m * ldc + n];
            C[(size_t)m * ldc + n] = v;
        }
    }
}

// ---------------------------------------------------------------------------
// x_proj split-K skinny GEMM (partials)
// ---------------------------------------------------------------------------
__global__ __launch_bounds__(256) void xproj_partial_kernel(
    const float* __restrict__ A,    // hconv [ROWS, DI]
    const float* __restrict__ W,    // x_proj_w [SSMW, DI]
    float* __restrict__ part)       // [XP_KS, ROWS, SSMW]
{
    __shared__ float sA[32*97];
    __shared__ float sW[80*97];
    const int m0 = blockIdx.x * 32;
    const int k0 = blockIdx.y * XP_KC;

    for (int idx = threadIdx.x; idx < 32*XP_KC; idx += 256) {
        int r = idx / XP_KC, k = idx % XP_KC;
        sA[r*97 + k] = A[(size_t)(m0 + r)*DI + k0 + k];
    }
    for (int idx = threadIdx.x; idx < 80*XP_KC; idx += 256) {
        int r = idx / XP_KC, k = idx % XP_KC;
        sW[r*97 + k] = W[(size_t)r*DI + k0 + k];
    }
    __syncthreads();

    const int tr = (threadIdx.x >> 4) * 2;
    const int tc = (threadIdx.x & 15) * 5;
    float acc[2][5];
    #pragma unroll
    for (int i = 0; i < 2; i++)
        #pragma unroll
        for (int j = 0; j < 5; j++) acc[i][j] = 0.f;

    #pragma unroll 4
    for (int k = 0; k < XP_KC; ++k) {
        float a0 = sA[tr*97 + k];
        float a1 = sA[(tr+1)*97 + k];
        float w0 = sW[(tc+0)*97 + k];
        float w1 = sW[(tc+1)*97 + k];
        float w2 = sW[(tc+2)*97 + k];
        float w3 = sW[(tc+3)*97 + k];
        float w4 = sW[(tc+4)*97 + k];
        acc[0][0] += a0*w0; acc[0][1] += a0*w1; acc[0][2] += a0*w2;
        acc[0][3] += a0*w3; acc[0][4] += a0*w4;
        acc[1][0] += a1*w0; acc[1][1] += a1*w1; acc[1][2] += a1*w2;
        acc[1][3] += a1*w3; acc[1][4] += a1*w4;
    }

    float* pp = part + ((size_t)blockIdx.y * ROWS + m0) * SSMW;
    #pragma unroll
    for (int i = 0; i < 2; i++)
        #pragma unroll
        for (int j = 0; j < 5; j++)
            pp[(size_t)(tr + i)*SSMW + tc + j] = acc[i][j];
}

// ---------------------------------------------------------------------------
// Fused: x_proj partial reduce + ssm write (by==0) + dt_proj GEMM + softplus.
// Grid (ROWS/32, DI/DTB). K=48 only for the GEMM.
// ---------------------------------------------------------------------------
__global__ __launch_bounds__(256) void xred_dtproj_kernel(
    const float* __restrict__ part,   // [XP_KS, ROWS, SSMW]
    const float* __restrict__ dpw,    // [DI, DTR]
    const float* __restrict__ dpb,    // [DI]
    float* __restrict__ ssmout,       // [ROWS, SSMW]
    float* __restrict__ dtb)          // [ROWS, DI]
{
    __shared__ float sA[32*81];
    __shared__ float sW[DTB*49];
    const int m0 = blockIdx.x * 32;
    const int n0 = blockIdx.y * DTB;

    if (blockIdx.y == 0) {
        for (int idx = threadIdx.x; idx < 32*SSMW; idx += 256) {
            int r = idx / SSMW, cc = idx % SSMW;
            float s = 0.f;
            #pragma unroll
            for (int ks = 0; ks < XP_KS; ++ks)
                s += part[(size_t)ks*ROWS*SSMW + (size_t)(m0+r)*SSMW + cc];
            if (cc < DTR) sA[r*81 + cc] = s;
            ssmout[(size_t)(m0+r)*SSMW + cc] = s;
        }
    } else {
        for (int idx = threadIdx.x; idx < 32*DTR; idx += 256) {
            int r = idx / DTR, cc = idx % DTR;
            float s = 0.f;
            #pragma unroll
            for (int ks = 0; ks < XP_KS; ++ks)
                s += part[(size_t)ks*ROWS*SSMW + (size_t)(m0+r)*SSMW + cc];
            sA[r*81 + cc] = s;
        }
    }
    for (int idx = threadIdx.x; idx < DTB*DTR; idx += 256) {
        int n = idx / DTR, k = idx % DTR;
        sW[n*49 + k] = dpw[(size_t)(n0+n)*DTR + k];
    }
    __syncthreads();

    const int tr = (threadIdx.x >> 4) * 2;   // 0..30
    const int tc = (threadIdx.x & 15) * 6;   // 0..90
    float acc[2][6];
    #pragma unroll
    for (int i = 0; i < 2; i++)
        #pragma unroll
        for (int j = 0; j < 6; j++) acc[i][j] = 0.f;

    #pragma unroll 4
    for (int k = 0; k < DTR; ++k) {
        float a0 = sA[tr*81 + k];
        float a1 = sA[(tr+1)*81 + k];
        #pragma unroll
        for (int j = 0; j < 6; ++j) {
            float wv = sW[(tc+j)*49 + k];
            acc[0][j] += a0*wv;
            acc[1][j] += a1*wv;
        }
    }
    #pragma unroll
    for (int i = 0; i < 2; ++i)
        #pragma unroll
        for (int j = 0; j < 6; ++j) {
            float v = acc[i][j] + dpb[n0 + tc + j];
            v = fmaxf(v, 0.f) + log1pf(expf(-fabsf(v)));   // softplus
            dtb[(size_t)(m0 + tr + i)*DI + n0 + tc + j] = v;
        }
}

// ---------------------------------------------------------------------------
// Causal depthwise conv (k=4) + SiLU
// ---------------------------------------------------------------------------
__global__ __launch_bounds__(256) void conv_silu_kernel(
    const float* __restrict__ proj,
    const float* __restrict__ cw, const float* __restrict__ cb,
    float* __restrict__ hconv)
{
    int idx = blockIdx.x * 256 + threadIdx.x;
    if (idx >= ROWS * DI) return;
    int d = idx % DI;
    int bt = idx / DI;
    int t = bt % LL;
    float sum = cb[d];
    #pragma unroll
    for (int j = 0; j < DCONV; j++) {
        int tt = t - (DCONV - 1) + j;
        if (tt >= 0)
            sum += cw[d * DCONV + j] * proj[(size_t)(bt - (DCONV - 1) + j) * (2 * DI) + d];
    }
    float sig = 1.f / (1.f + expf(-sum));
    hconv[idx] = sum * sig;
}

// ---------------------------------------------------------------------------
// Chunked selective scan — pass 1: per-chunk local scan
// ---------------------------------------------------------------------------
__global__ __launch_bounds__(256) void scan_local_kernel(
    const float* __restrict__ dt, const float* __restrict__ hconv,
    const float* __restrict__ ssm, const float* __restrict__ A_log,
    float* __restrict__ ylocal, float* __restrict__ E, float* __restrict__ P)
{
    const int tid = threadIdx.x;
    const int s  = tid & 15;
    const int dg = tid >> 4;
    int blk = blockIdx.x;
    const int dblk = blk % NDB; blk /= NDB;
    const int c = blk % NC;
    const int b = blk / NC;
    const int d = dblk * 16 + dg;

    const float Ads = -expf(A_log[(size_t)d * DS + s]);
    float state = 0.f, Ssum = 0.f;
    const int t0 = c * CL;
    const float* dtp = dt     + ((size_t)b*LL + t0)*DI + d;
    const float* hp  = hconv  + ((size_t)b*LL + t0)*DI + d;
    const float* sp  = ssm    + ((size_t)b*LL + t0)*SSMW;
    float*       yp  = ylocal + ((size_t)b*LL + t0)*DI + d;

    for (int t = 0; t < CL; ++t) {
        float dtv = dtp[(size_t)t * DI];
        float hv  = hp[(size_t)t * DI];
        float Bv  = sp[(size_t)t * SSMW + DTR + s];
        float Cv  = sp[(size_t)t * SSMW + DTR + DS + s];
        float dA  = expf(dtv * Ads);
        state = dA * state + dtv * hv * Bv;
        Ssum += dtv;
        float contrib = state * Cv;
        contrib += __shfl_xor(contrib, 1, 16);
        contrib += __shfl_xor(contrib, 2, 16);
        contrib += __shfl_xor(contrib, 4, 16);
        contrib += __shfl_xor(contrib, 8, 16);
        if (s == 0) yp[(size_t)t * DI] = contrib;
    }
    const size_t si = (((size_t)b*NC + c)*DI + d)*DS + s;
    E[si] = state;
    P[si] = expf(Ads * Ssum);
}

// ---------------------------------------------------------------------------
// Pass 2 (fused carry): each block replays carry recurrence from E/P, then
// fix-up + epilogue. PLANES=1 -> write bf16 hi/lo planes for out_proj.
// ---------------------------------------------------------------------------
template<int PLANES>
__global__ __launch_bounds__(256) void scan_fix_kernel(
    const float* __restrict__ dt, const float* __restrict__ hconv,
    const float* __restrict__ ssm, const float* __restrict__ proj,
    const float* __restrict__ A_log, const float* __restrict__ D_skip,
    const float* __restrict__ E, const float* __restrict__ P,
    float* __restrict__ y,
    unsigned short* __restrict__ yhi, unsigned short* __restrict__ ylo)
{
    const int tid = threadIdx.x;
    const int s  = tid & 15;
    const int dg = tid >> 4;
    int blk = blockIdx.x;
    const int dblk = blk % NDB; blk /= NDB;
    const int c = blk % NC;
    const int b = blk / NC;
    const int d = dblk * 16 + dg;

    const float Ads = -expf(A_log[(size_t)d * DS + s]);
    const float Dd  = D_skip[d];

    // inline carry: cv = carry for chunk c at (b,d,s)
    float cv = 0.f;
    {
        const size_t epbase = ((size_t)b*NC)*(size_t)(DI*DS) + (size_t)d*DS + s;
        for (int j = 0; j < c; ++j) {
            size_t idx = epbase + (size_t)j*(DI*DS);
            cv = P[idx] * cv + E[idx];
        }
    }

    float S = 0.f;
    const int t0 = c * CL;
    const float* dtp = dt    + ((size_t)b*LL + t0)*DI + d;
    const float* hp  = hconv + ((size_t)b*LL + t0)*DI + d;
    const float* sp  = ssm   + ((size_t)b*LL + t0)*SSMW;
    const float* gp  = proj  + ((size_t)b*LL + t0)*(2*DI) + DI + d;
    const size_t yoff = ((size_t)b*LL + t0)*DI + d;

    for (int t = 0; t < CL; ++t) {
        float dtv = dtp[(size_t)t * DI];
        S += dtv;
        float Cv = sp[(size_t)t * SSMW + DTR + DS + s];
        float contrib = expf(Ads * S) * cv * Cv;
        contrib += __shfl_xor(contrib, 1, 16);
        contrib += __shfl_xor(contrib, 2, 16);
        contrib += __shfl_xor(contrib, 4, 16);
        contrib += __shfl_xor(contrib, 8, 16);
        if (s == 0) {
            float hv  = hp[(size_t)t * DI];
            float ylv = y[yoff + (size_t)t * DI];
            float gv  = gp[(size_t)t * (2*DI)];
            float sig = 1.f / (1.f + expf(-gv));
            float yv  = (ylv + contrib + Dd * hv) * (gv * sig);
            if (PLANES) {
                unsigned short hh = f2bf(yv);
                yhi[yoff + (size_t)t * DI] = hh;
                ylo[yoff + (size_t)t * DI] = f2bf(yv - bf2f(hh));
            } else {
                y[yoff + (size_t)t * DI] = yv;
            }
        }
    }
}

// ---------------------------------------------------------------------------
// Launch
// ---------------------------------------------------------------------------
extern "C" void kernel_launch(void* const* d_in, const int* in_sizes, int n_in,
                              void* d_out, int out_size, void* d_ws, size_t ws_size,
                              hipStream_t stream)
{
    const int*   ids        = (const int*)  d_in[0];
    const float* embed      = (const float*)d_in[1];
    const float* norm_f_w   = (const float*)d_in[2];
    const float* in_proj_w  = (const float*)d_in[3];
    const float* conv_w     = (const float*)d_in[4];
    const float* conv_b     = (const float*)d_in[5];
    const float* x_proj_w   = (const float*)d_in[6];
    const float* dt_proj_w  = (const float*)d_in[7];
    const float* dt_proj_b  = (const float*)d_in[8];
    const float* A_log      = (const float*)d_in[9];
    const float* D_skip     = (const float*)d_in[10];
    const float* out_proj_w = (const float*)d_in[11];
    const float* norm_w     = (const float*)d_in[12];
    float* out = (float*)d_out;

    // fp32 workspace region
    float* ws    = (float*)d_ws;
    float* h     = ws;
    float* xn    = h     + ROWS * DM;               // fallback only
    float* proj  = xn    + ROWS * DM;
    float* hconv = proj  + ROWS * 2 * DI;
    float* ssm   = hconv + ROWS * DI;
    float* dtb   = ssm   + ROWS * SSMW;
    float* yb    = dtb   + ROWS * DI;
    float* Ebuf  = yb    + ROWS * DI;
    float* Pbuf  = Ebuf  + (size_t)BB*NC*DI*DS;
    float* xpart = Pbuf  + (size_t)BB*NC*DI*DS;      // [XP_KS, ROWS, SSMW]
    float* opart = xpart + (size_t)XP_KS*ROWS*SSMW;  // [OP_KS, ROWS, DM]
    const size_t F32_FLOATS = (size_t)ROWS * (DM + DM + 2*DI + DI + SSMW + DI + DI)
                            + 2 * (size_t)BB*NC*DI*DS
                            + (size_t)XP_KS*ROWS*SSMW
                            + (size_t)OP_KS*ROWS*DM;

    // bf16 split planes (embed LAST so tier-1 works with smaller ws)
    const size_t IPW_E = (size_t)NL * 2 * DI * DM;
    const size_t OPW_E = (size_t)NL * DM * DI;
    const size_t ACT_E = (size_t)ROWS * DI;
    const size_t EMB_E = (size_t)VOCAB_ * DM;
    unsigned short* u0   = (unsigned short*)(ws + F32_FLOATS);
    unsigned short* ipwh = u0;
    unsigned short* ipwl = ipwh + IPW_E;
    unsigned short* opwh = ipwl + IPW_E;
    unsigned short* opwl = opwh + OPW_E;
    unsigned short* acth = opwl + OPW_E;
    unsigned short* actl = acth + ACT_E;
    unsigned short* embh = actl + ACT_E;
    unsigned short* embl = embh + EMB_E;
    const size_t NEED_PROJ = F32_FLOATS*4 + 2*2*(IPW_E + OPW_E + ACT_E);
    const size_t NEED_HEAD = NEED_PROJ + 2*2*EMB_E;
    const bool mfma_proj = ws_size >= NEED_PROJ;
    const bool mfma_head = ws_size >= NEED_HEAD;

    if (mfma_proj) {
        split_kernel<<<(int)(IPW_E/4 + 255)/256, 256, 0, stream>>>(in_proj_w,  ipwh, ipwl, (int)(IPW_E/4));
        split_kernel<<<(int)(OPW_E/4 + 255)/256, 256, 0, stream>>>(out_proj_w, opwh, opwl, (int)(OPW_E/4));
        // fused gather + layer-0 norm + planes
        gather_norm_kernel<<<ROWS, 256, 0, stream>>>(ids, embed, norm_w, h, acth, actl);
    } else {
        gather_kernel<<<(ROWS * DM + 255) / 256, 256, 0, stream>>>(ids, embed, h, ROWS * DM);
    }
    if (mfma_head) {
        split_kernel<<<(int)(EMB_E/4 + 255)/256, 256, 0, stream>>>(embed, embh, embl, (int)(EMB_E/4));
    }

    for (int i = 0; i < NL; ++i) {
        const float* ipw = in_proj_w  + (size_t)i * 2 * DI * DM;
        const float* cw  = conv_w     + (size_t)i * DI * DCONV;
        const float* cb  = conv_b     + (size_t)i * DI;
        const float* xpw = x_proj_w   + (size_t)i * SSMW * DI;
        const float* dpw = dt_proj_w  + (size_t)i * DI * DTR;
        const float* dpb = dt_proj_b  + (size_t)i * DI;
        const float* al  = A_log      + (size_t)i * DI * DS;
        const float* dsk = D_skip     + (size_t)i * DI;
        const float* opw = out_proj_w + (size_t)i * DM * DI;
        // norm weight applied AFTER this layer's residual add:
        const float* nwNext = (i < NL-1) ? (norm_w + (size_t)(i+1) * DM) : norm_f_w;

        if (mfma_proj) {
            // planes already hold rmsnorm(h) for this layer
            gemm_mfma<0><<<dim3(8*24, 1), 256, 0, stream>>>(
                acth, actl, DM, ipwh + (size_t)i*2*DI*DM, ipwl + (size_t)i*2*DI*DM, DM,
                proj, 2*DI, DM, nullptr, 8, 0);
        } else {
            rmsnorm_kernel<<<ROWS, 256, 0, stream>>>(h, norm_w + (size_t)i*DM, xn, DM);
            gemm_tn<0><<<dim3(ROWS/64, (2*DI)/64), 256, 0, stream>>>(
                xn, DM, ipw, DM, proj, 2*DI, ROWS, 2*DI, DM, nullptr, nullptr);
        }

        conv_silu_kernel<<<(ROWS * DI + 255) / 256, 256, 0, stream>>>(proj, cw, cb, hconv);

        // x_proj partials + fused (reduce -> ssm, dt GEMM -> softplus -> dtb)
        xproj_partial_kernel<<<dim3(ROWS/32, XP_KS), 256, 0, stream>>>(hconv, xpw, xpart);
        xred_dtproj_kernel<<<dim3(ROWS/32, DI/DTB), 256, 0, stream>>>(xpart, dpw, dpb, ssm, dtb);

        // chunked scan: local -> fix (carry inlined)
        scan_local_kernel<<<BB*NC*NDB, 256, 0, stream>>>(dtb, hconv, ssm, al, yb, Ebuf, Pbuf);

        if (mfma_proj) {
            scan_fix_kernel<1><<<BB*NC*NDB, 256, 0, stream>>>(
                dtb, hconv, ssm, proj, al, dsk, Ebuf, Pbuf, yb, acth, actl);
            // out_proj split-K (4 x 48 blocks)
            gemm_mfma<0><<<dim3(8*6, OP_KS), 256, 0, stream>>>(
                acth, actl, DI, opwh + (size_t)i*DM*DI, opwl + (size_t)i*DM*DI, DI,
                opart, DM, OP_KC, nullptr, 8, (size_t)ROWS*DM);
            // fused: reduce + residual + next norm + planes
            opreduce_norm_kernel<<<ROWS, 256, 0, stream>>>(opart, nwNext, h, acth, actl);
        } else {
            scan_fix_kernel<0><<<BB*NC*NDB, 256, 0, stream>>>(
                dtb, hconv, ssm, proj, al, dsk, Ebuf, Pbuf, yb, nullptr, nullptr);
            gemm_tn<2><<<dim3(ROWS/64, DM/64), 256, 0, stream>>>(
                yb, DI, opw, DI, h, DM, ROWS, DM, DI, nullptr, h);
        }
    }

    if (mfma_head) {
        // planes hold norm_f(h) after last opreduce_norm
        gemm_mfma<0><<<dim3(8*250, 1), 256, 0, stream>>>(
            acth, actl, DM, embh, embl, DM, out, VOCAB_, DM, nullptr, 8, 0);
    } else {
        rmsnorm_kernel<<<ROWS, 256, 0, stream>>>(h, norm_f_w, xn, DM);
        gemm_tn<0><<<dim3(ROWS/64, VOCAB_/64), 256, 0, stream>>>(
            xn, DM, embed, DM, out, VOCAB_, ROWS, VOCAB_, DM, nullptr, nullptr);
    }
}